// Round 1
// baseline (1125.386 us; speedup 1.0000x reference)
//
#include <hip/hip_runtime.h>
#include <math.h>

#define NN 100000   // nodes
#define NE 300000   // edges
#define NG 2000     // graphs
#define HID 256
#define CIN 59
#define EPSV 1e-5f

#define SCAN_CHUNK 1024
#define NCHUNK ((NN + SCAN_CHUNK - 1) / SCAN_CHUNK)   // 98

// ---------------- degree / CSR build ----------------

__global__ __launch_bounds__(256) void k_deg(const int* __restrict__ ei, int* __restrict__ deg) {
  int e = blockIdx.x * 256 + threadIdx.x;
  if (e < NE) atomicAdd(&deg[ei[NE + e]], 1);   // dst = ei[1][e]
}

__global__ __launch_bounds__(256) void k_dinv(const int* __restrict__ deg, float* __restrict__ dinv) {
  int i = blockIdx.x * 256 + threadIdx.x;
  if (i < NN) dinv[i] = rsqrtf((float)deg[i] + 1.0f);  // +1 self loop
}

__global__ __launch_bounds__(256) void k_scanA(const int* __restrict__ deg, int* __restrict__ part) {
  __shared__ int sm[256];
  int b = blockIdx.x, t = threadIdx.x;
  int base = b * SCAN_CHUNK + t * 4;
  int s = 0;
#pragma unroll
  for (int j = 0; j < 4; ++j) { int idx = base + j; if (idx < NN) s += deg[idx]; }
  sm[t] = s; __syncthreads();
  for (int off = 128; off > 0; off >>= 1) {
    if (t < off) sm[t] += sm[t + off];
    __syncthreads();
  }
  if (t == 0) part[b] = sm[0];
}

__global__ void k_scanB(int* __restrict__ part) {  // launch with 128 threads
  __shared__ int sm[128];
  int t = threadIdx.x;
  int v = (t < NCHUNK) ? part[t] : 0;
  sm[t] = v; __syncthreads();
  for (int off = 1; off < 128; off <<= 1) {
    int x = (t >= off) ? sm[t - off] : 0;
    __syncthreads();
    sm[t] += x;
    __syncthreads();
  }
  if (t < NCHUNK) part[t] = sm[t] - v;  // exclusive
}

__global__ __launch_bounds__(256) void k_scanC(const int* __restrict__ deg, const int* __restrict__ part,
                                               int* __restrict__ row_start, int* __restrict__ pos) {
  __shared__ int sm[256];
  int b = blockIdx.x, t = threadIdx.x;
  int base = b * SCAN_CHUNK + t * 4;
  int v[4]; int s = 0;
#pragma unroll
  for (int j = 0; j < 4; ++j) { int idx = base + j; v[j] = (idx < NN) ? deg[idx] : 0; s += v[j]; }
  sm[t] = s; __syncthreads();
  for (int off = 1; off < 256; off <<= 1) {
    int x = (t >= off) ? sm[t - off] : 0;
    __syncthreads();
    sm[t] += x;
    __syncthreads();
  }
  int excl = sm[t] - s + part[b];
#pragma unroll
  for (int j = 0; j < 4; ++j) {
    int idx = base + j;
    if (idx < NN) { row_start[idx] = excl; pos[idx] = excl; excl += v[j]; }
  }
  if (b == 0 && t == 0) row_start[NN] = NE;  // total degree == E always
}

__global__ __launch_bounds__(256) void k_csr_fill(const int* __restrict__ ei, int* __restrict__ pos,
                                                  int* __restrict__ csr_src) {
  int e = blockIdx.x * 256 + threadIdx.x;
  if (e >= NE) return;
  int d = ei[NE + e];
  int slot = atomicAdd(&pos[d], 1);
  csr_src[slot] = ei[e];
}

// graph start offsets from sorted batch
__global__ __launch_bounds__(256) void k_gstart(const int* __restrict__ batch, int* __restrict__ gstart) {
  int i = blockIdx.x * 256 + threadIdx.x;
  if (i >= NN) return;
  int b = batch[i];
  int pb = (i == 0) ? -1 : batch[i - 1];
  for (int g = pb + 1; g <= b; ++g) gstart[g] = i;
  if (i == NN - 1) {
    for (int g = b + 1; g <= NG; ++g) gstart[g] = NN;
  }
}

// ---------------- lin0 + ELU ----------------
// block = 256 threads (one per output channel), 32 nodes per block.
__global__ __launch_bounds__(256) void k_lin0(const float* __restrict__ x, const float* __restrict__ W,
                                              const float* __restrict__ bias, float* __restrict__ H) {
  __shared__ float xs[32 * CIN];
  int tid = threadIdx.x;
  int n0 = blockIdx.x * 32;
  for (int idx = tid; idx < 32 * CIN; idx += 256) xs[idx] = x[(size_t)n0 * CIN + idx];
  __syncthreads();
  float acc[32];
  float b = bias[tid];
#pragma unroll
  for (int n = 0; n < 32; ++n) acc[n] = b;
  const float* wr = W + tid * CIN;
  for (int k = 0; k < CIN; ++k) {
    float w = wr[k];
#pragma unroll
    for (int n = 0; n < 32; ++n) acc[n] = fmaf(xs[n * CIN + k], w, acc[n]);
  }
#pragma unroll
  for (int n = 0; n < 32; ++n) {
    float v = acc[n];
    v = v > 0.f ? v : expm1f(v);                 // ELU
    H[(size_t)(n0 + n) * HID + tid] = v;
  }
}

// ---------------- GEMM: C[m][n] = sum_k A[m][k] * B[n][k]  (B = conv_W layer, row-major [n][k]) ----------------
#define BM 128
#define BN 128
#define BK 32
__global__ __launch_bounds__(256) void k_gemm(const float* __restrict__ A, const float* __restrict__ B,
                                              float* __restrict__ C, int M) {
  __shared__ float As[BM][BK + 1];   // row-major, pad -> conflict-free a reads
  __shared__ float Bs[BK][BN + 4];   // k-major, 16B-aligned rows
  int tid = threadIdx.x;
  int tx = tid & 15, ty = tid >> 4;
  int m0 = blockIdx.x * BM, n0 = blockIdx.y * BN;
  float acc[8][8];
#pragma unroll
  for (int i = 0; i < 8; ++i)
#pragma unroll
    for (int j = 0; j < 8; ++j) acc[i][j] = 0.f;

  int lr = tid >> 3;               // 0..31
  int lc = (tid & 7) << 2;         // 0,4,...,28
  for (int k0 = 0; k0 < HID; k0 += BK) {
#pragma unroll
    for (int r = 0; r < 4; ++r) {
      int row = lr + r * 32;
      int m = m0 + row;
      float4 v = make_float4(0.f, 0.f, 0.f, 0.f);
      if (m < M) v = *(const float4*)(A + (size_t)m * HID + k0 + lc);
      As[row][lc + 0] = v.x; As[row][lc + 1] = v.y; As[row][lc + 2] = v.z; As[row][lc + 3] = v.w;
    }
#pragma unroll
    for (int r = 0; r < 4; ++r) {
      int nn = lr + r * 32;
      float4 v = *(const float4*)(B + (size_t)(n0 + nn) * HID + k0 + lc);
      Bs[lc + 0][nn] = v.x; Bs[lc + 1][nn] = v.y; Bs[lc + 2][nn] = v.z; Bs[lc + 3][nn] = v.w;
    }
    __syncthreads();
#pragma unroll
    for (int k = 0; k < BK; ++k) {
      float a[8];
#pragma unroll
      for (int i = 0; i < 8; ++i) a[i] = As[ty * 8 + i][k];
      float4 b0 = *(const float4*)&Bs[k][tx * 8];
      float4 b1 = *(const float4*)&Bs[k][tx * 8 + 4];
      float bf[8] = {b0.x, b0.y, b0.z, b0.w, b1.x, b1.y, b1.z, b1.w};
#pragma unroll
      for (int i = 0; i < 8; ++i)
#pragma unroll
        for (int j = 0; j < 8; ++j) acc[i][j] = fmaf(a[i], bf[j], acc[i][j]);
    }
    __syncthreads();
  }
#pragma unroll
  for (int i = 0; i < 8; ++i) {
    int m = m0 + ty * 8 + i;
    if (m < M) {
      float4 o0 = make_float4(acc[i][0], acc[i][1], acc[i][2], acc[i][3]);
      float4 o1 = make_float4(acc[i][4], acc[i][5], acc[i][6], acc[i][7]);
      *(float4*)(C + (size_t)m * HID + n0 + tx * 8) = o0;
      *(float4*)(C + (size_t)m * HID + n0 + tx * 8 + 4) = o1;
    }
  }
}

// ---------------- aggregate: one wave per dst node ----------------
__global__ __launch_bounds__(256) void k_aggregate(const float* __restrict__ T, const float* __restrict__ dinv,
                                                   const int* __restrict__ row_start, const int* __restrict__ csr_src,
                                                   const float* __restrict__ bias, float* __restrict__ H) {
  int wid = blockIdx.x * 4 + (threadIdx.x >> 6);
  int lane = threadIdx.x & 63;
  if (wid >= NN) return;
  float di = dinv[wid];
  int s = row_start[wid], e = row_start[wid + 1];
  float4 acc = make_float4(0.f, 0.f, 0.f, 0.f);
  for (int t = s; t < e; ++t) {
    int src = csr_src[t];
    float c = dinv[src] * di;
    float4 v = ((const float4*)(T + (size_t)src * HID))[lane];
    acc.x = fmaf(v.x, c, acc.x); acc.y = fmaf(v.y, c, acc.y);
    acc.z = fmaf(v.z, c, acc.z); acc.w = fmaf(v.w, c, acc.w);
  }
  float4 v = ((const float4*)(T + (size_t)wid * HID))[lane];
  float sc = di * di;
  float4 bb = ((const float4*)bias)[lane];
  acc.x = fmaf(v.x, sc, acc.x) + bb.x;
  acc.y = fmaf(v.y, sc, acc.y) + bb.y;
  acc.z = fmaf(v.z, sc, acc.z) + bb.z;
  acc.w = fmaf(v.w, sc, acc.w) + bb.w;
  ((float4*)(H + (size_t)wid * HID))[lane] = acc;
}

// ---------------- GraphNorm (+ReLU, + pool on last layer), in-place ----------------
__global__ __launch_bounds__(256) void k_gnorm(float* __restrict__ H, const int* __restrict__ gstart,
                                               const float* __restrict__ alpha, const float* __restrict__ gamma,
                                               const float* __restrict__ beta, float* __restrict__ pooled,
                                               int last) {
  int g = blockIdx.x, c = threadIdx.x;
  int s = gstart[g], e = gstart[g + 1];
  int n = e - s;
  float cnt = (float)(n > 1 ? n : 1);
  float s1 = 0.f, s2 = 0.f;
  for (int i = s; i < e; ++i) {
    float v = H[(size_t)i * HID + c];
    s1 += v; s2 = fmaf(v, v, s2);
  }
  float mean = s1 / cnt;
  float am = alpha[c] * mean;
  float var = s2 / cnt - 2.f * am * mean + am * am;   // E[(h-am)^2]
  float rs = rsqrtf(var + EPSV);
  float ga = gamma[c], be = beta[c];
  if (last) {
    float pool = 0.f;
    for (int i = s; i < e; ++i) {
      float v = H[(size_t)i * HID + c];
      float o = fmaxf((v - am) * rs * ga + be, 0.f);
      pool += o;
    }
    pooled[g * HID + c] = pool;
  } else {
    for (int i = s; i < e; ++i) {
      float v = H[(size_t)i * HID + c];
      H[(size_t)i * HID + c] = fmaxf((v - am) * rs * ga + be, 0.f);
    }
  }
}

// ---------------- W1 transpose (for coalesced head reads) ----------------
__global__ void k_transpose(const float* __restrict__ W, float* __restrict__ Wt) {
  __shared__ float tile[32][33];
  int bx = blockIdx.x, by = blockIdx.y;
  int tx = threadIdx.x, ty = threadIdx.y;   // 32 x 8
  for (int r = 0; r < 32; r += 8)
    tile[ty + r][tx] = W[(size_t)(by * 32 + ty + r) * HID + bx * 32 + tx];
  __syncthreads();
  for (int r = 0; r < 32; r += 8)
    Wt[(size_t)(bx * 32 + ty + r) * HID + by * 32 + tx] = tile[tx][ty + r];
}

// ---------------- head: relu(g@W1^T + b1) -> dot out_W -> sigmoid ----------------
__global__ __launch_bounds__(256) void k_head(const float* __restrict__ pooled, const float* __restrict__ W1t,
                                              const float* __restrict__ b1, const float* __restrict__ Wout,
                                              const float* __restrict__ bout, float* __restrict__ out) {
  int g = blockIdx.x, t = threadIdx.x;
  __shared__ float gv[HID];
  __shared__ float red[HID];
  gv[t] = pooled[g * HID + t];
  __syncthreads();
  float acc = b1[t];
  for (int k = 0; k < HID; ++k) acc = fmaf(gv[k], W1t[k * HID + t], acc);
  float h = fmaxf(acc, 0.f);
  red[t] = h * Wout[t];
  __syncthreads();
  for (int off = 128; off > 0; off >>= 1) {
    if (t < off) red[t] += red[t + off];
    __syncthreads();
  }
  if (t == 0) out[g] = 1.f / (1.f + expf(-(red[0] + bout[0])));
}

// ---------------- launch ----------------
extern "C" void kernel_launch(void* const* d_in, const int* in_sizes, int n_in,
                              void* d_out, int out_size, void* d_ws, size_t ws_size,
                              hipStream_t stream) {
  const float* x          = (const float*)d_in[0];
  const int*   edge_index = (const int*)d_in[1];
  const int*   batch      = (const int*)d_in[2];
  const float* lin0_W     = (const float*)d_in[3];
  const float* lin0_b     = (const float*)d_in[4];
  const float* conv_W     = (const float*)d_in[5];
  const float* conv_b     = (const float*)d_in[6];
  const float* n_alpha    = (const float*)d_in[7];
  const float* n_gamma    = (const float*)d_in[8];
  const float* n_beta     = (const float*)d_in[9];
  const float* lin1_W     = (const float*)d_in[10];
  const float* lin1_b     = (const float*)d_in[11];
  const float* out_W      = (const float*)d_in[12];
  const float* out_b      = (const float*)d_in[13];
  float* out = (float*)d_out;

  char* ws = (char*)d_ws;
  size_t off = 0;
  auto nxt = [&](size_t bytes) { size_t o = off; off += (bytes + 255) & ~(size_t)255; return o; };
  float* hA      = (float*)(ws + nxt((size_t)NN * HID * 4));
  float* Tbuf    = (float*)(ws + nxt((size_t)NN * HID * 4));
  float* dinv    = (float*)(ws + nxt((size_t)NN * 4));
  int*   deg     = (int*)  (ws + nxt((size_t)NN * 4));
  int*   rstart  = (int*)  (ws + nxt((size_t)(NN + 1) * 4));
  int*   pos     = (int*)  (ws + nxt((size_t)NN * 4));
  int*   csrsrc  = (int*)  (ws + nxt((size_t)NE * 4));
  int*   gstart  = (int*)  (ws + nxt((size_t)(NG + 1) * 4));
  float* pooled  = (float*)(ws + nxt((size_t)NG * HID * 4));
  float* W1t     = (float*)(ws + nxt((size_t)HID * HID * 4));
  int*   part    = (int*)  (ws + nxt((size_t)NCHUNK * 4));
  (void)ws_size; (void)in_sizes; (void)n_in; (void)out_size;

  hipMemsetAsync(deg, 0, (size_t)NN * 4, stream);
  k_deg<<<(NE + 255) / 256, 256, 0, stream>>>(edge_index, deg);
  k_dinv<<<(NN + 255) / 256, 256, 0, stream>>>(deg, dinv);
  k_scanA<<<NCHUNK, 256, 0, stream>>>(deg, part);
  k_scanB<<<1, 128, 0, stream>>>(part);
  k_scanC<<<NCHUNK, 256, 0, stream>>>(deg, part, rstart, pos);
  k_csr_fill<<<(NE + 255) / 256, 256, 0, stream>>>(edge_index, pos, csrsrc);
  k_gstart<<<(NN + 255) / 256, 256, 0, stream>>>(batch, gstart);
  k_lin0<<<NN / 32, 256, 0, stream>>>(x, lin0_W, lin0_b, hA);
  k_transpose<<<dim3(8, 8), dim3(32, 8), 0, stream>>>(lin1_W, W1t);

  for (int l = 0; l < 3; ++l) {
    k_gemm<<<dim3((NN + BM - 1) / BM, HID / BN), 256, 0, stream>>>(hA, conv_W + (size_t)l * HID * HID, Tbuf, NN);
    k_aggregate<<<(NN + 3) / 4, 256, 0, stream>>>(Tbuf, dinv, rstart, csrsrc, conv_b + l * HID, hA);
    k_gnorm<<<NG, 256, 0, stream>>>(hA, gstart, n_alpha + l * HID, n_gamma + l * HID, n_beta + l * HID,
                                    pooled, l == 2 ? 1 : 0);
  }
  k_head<<<NG, 256, 0, stream>>>(pooled, W1t, lin1_b, out_W, out_b, out);
}

// Round 2
// 907.731 us; speedup vs baseline: 1.2398x; 1.2398x over previous
//
#include <hip/hip_runtime.h>
#include <math.h>

#define NN 100000   // nodes
#define NE 300000   // edges
#define NG 2000     // graphs
#define HID 256
#define CIN 59
#define EPSV 1e-5f

#define SCAN_CHUNK 1024
#define NCHUNK ((NN + SCAN_CHUNK - 1) / SCAN_CHUNK)   // 98

typedef __attribute__((ext_vector_type(8))) short bf16x8;   // 8 bf16 (4 VGPRs)
typedef __attribute__((ext_vector_type(4))) float f32x4;

// ---------- f32 -> (bf16 hi, bf16 lo) split, round-to-nearest ----------
__device__ inline void splitbf(float x, ushort& hi, ushort& lo) {
  union { float f; unsigned u; } a; a.f = x;
  unsigned r = a.u + 0x7FFFu + ((a.u >> 16) & 1u);
  hi = (ushort)(r >> 16);
  union { unsigned u; float f; } h; h.u = (unsigned)hi << 16;
  union { float f; unsigned u; } d; d.f = x - h.f;
  unsigned r2 = d.u + 0x7FFFu + ((d.u >> 16) & 1u);
  lo = (ushort)(r2 >> 16);
}
__device__ inline float joinbf(ushort hi, ushort lo) {
  union { unsigned u; float f; } a, b;
  a.u = (unsigned)hi << 16; b.u = (unsigned)lo << 16;
  return a.f + b.f;
}

// ---------------- degree / CSR build ----------------

__global__ __launch_bounds__(256) void k_deg(const int* __restrict__ ei, int* __restrict__ deg) {
  int e = blockIdx.x * 256 + threadIdx.x;
  if (e < NE) atomicAdd(&deg[ei[NE + e]], 1);   // dst = ei[1][e]
}

__global__ __launch_bounds__(256) void k_dinv(const int* __restrict__ deg, float* __restrict__ dinv) {
  int i = blockIdx.x * 256 + threadIdx.x;
  if (i < NN) dinv[i] = rsqrtf((float)deg[i] + 1.0f);  // +1 self loop
}

__global__ __launch_bounds__(256) void k_scanA(const int* __restrict__ deg, int* __restrict__ part) {
  __shared__ int sm[256];
  int b = blockIdx.x, t = threadIdx.x;
  int base = b * SCAN_CHUNK + t * 4;
  int s = 0;
#pragma unroll
  for (int j = 0; j < 4; ++j) { int idx = base + j; if (idx < NN) s += deg[idx]; }
  sm[t] = s; __syncthreads();
  for (int off = 128; off > 0; off >>= 1) {
    if (t < off) sm[t] += sm[t + off];
    __syncthreads();
  }
  if (t == 0) part[b] = sm[0];
}

__global__ void k_scanB(int* __restrict__ part) {  // 128 threads
  __shared__ int sm[128];
  int t = threadIdx.x;
  int v = (t < NCHUNK) ? part[t] : 0;
  sm[t] = v; __syncthreads();
  for (int off = 1; off < 128; off <<= 1) {
    int x = (t >= off) ? sm[t - off] : 0;
    __syncthreads();
    sm[t] += x;
    __syncthreads();
  }
  if (t < NCHUNK) part[t] = sm[t] - v;  // exclusive
}

__global__ __launch_bounds__(256) void k_scanC(const int* __restrict__ deg, const int* __restrict__ part,
                                               int* __restrict__ row_start, int* __restrict__ pos) {
  __shared__ int sm[256];
  int b = blockIdx.x, t = threadIdx.x;
  int base = b * SCAN_CHUNK + t * 4;
  int v[4]; int s = 0;
#pragma unroll
  for (int j = 0; j < 4; ++j) { int idx = base + j; v[j] = (idx < NN) ? deg[idx] : 0; s += v[j]; }
  sm[t] = s; __syncthreads();
  for (int off = 1; off < 256; off <<= 1) {
    int x = (t >= off) ? sm[t - off] : 0;
    __syncthreads();
    sm[t] += x;
    __syncthreads();
  }
  int excl = sm[t] - s + part[b];
#pragma unroll
  for (int j = 0; j < 4; ++j) {
    int idx = base + j;
    if (idx < NN) { row_start[idx] = excl; pos[idx] = excl; excl += v[j]; }
  }
  if (b == 0 && t == 0) row_start[NN] = NE;
}

__global__ __launch_bounds__(256) void k_csr_fill(const int* __restrict__ ei, int* __restrict__ pos,
                                                  int* __restrict__ csr_src) {
  int e = blockIdx.x * 256 + threadIdx.x;
  if (e >= NE) return;
  int d = ei[NE + e];
  int slot = atomicAdd(&pos[d], 1);
  csr_src[slot] = ei[e];
}

__global__ __launch_bounds__(256) void k_gstart(const int* __restrict__ batch, int* __restrict__ gstart) {
  int i = blockIdx.x * 256 + threadIdx.x;
  if (i >= NN) return;
  int b = batch[i];
  int pb = (i == 0) ? -1 : batch[i - 1];
  for (int g = pb + 1; g <= b; ++g) gstart[g] = i;
  if (i == NN - 1) {
    for (int g = b + 1; g <= NG; ++g) gstart[g] = NN;
  }
}

// ---------------- conv_W -> bf16 hi/lo ----------------
__global__ __launch_bounds__(256) void k_wcvt(const float* __restrict__ W, ushort* __restrict__ Whi,
                                              ushort* __restrict__ Wlo, int n) {
  int i = blockIdx.x * 256 + threadIdx.x;
  if (i >= n) return;
  ushort h, l; splitbf(W[i], h, l);
  Whi[i] = h; Wlo[i] = l;
}

// ---------------- lin0 + ELU -> bf16 hi/lo ----------------
__global__ __launch_bounds__(256) void k_lin0(const float* __restrict__ x, const float* __restrict__ W,
                                              const float* __restrict__ bias,
                                              ushort* __restrict__ Ahi, ushort* __restrict__ Alo) {
  __shared__ float xs[32 * CIN];
  int tid = threadIdx.x;
  int n0 = blockIdx.x * 32;
  for (int idx = tid; idx < 32 * CIN; idx += 256) xs[idx] = x[(size_t)n0 * CIN + idx];
  __syncthreads();
  float acc[32];
  float b = bias[tid];
#pragma unroll
  for (int n = 0; n < 32; ++n) acc[n] = b;
  const float* wr = W + tid * CIN;
  for (int k = 0; k < CIN; ++k) {
    float w = wr[k];
#pragma unroll
    for (int n = 0; n < 32; ++n) acc[n] = fmaf(xs[n * CIN + k], w, acc[n]);
  }
#pragma unroll
  for (int n = 0; n < 32; ++n) {
    float v = acc[n];
    v = v > 0.f ? v : expm1f(v);                 // ELU
    ushort h, l; splitbf(v, h, l);
    Ahi[(size_t)(n0 + n) * HID + tid] = h;
    Alo[(size_t)(n0 + n) * HID + tid] = l;
  }
}

// ---------------- MFMA split-bf16 GEMM: C = A @ W^T ----------------
// block 128x128, 4 waves (2x2), each wave 64x64 (4x4 fragments of 16x16x32).
// 3-term: hi*hi + hi*lo + lo*hi ~ f32 precision.
__global__ __launch_bounds__(256) void k_gemm_mfma(const ushort* __restrict__ Ahi, const ushort* __restrict__ Alo,
                                                   const ushort* __restrict__ Whi, const ushort* __restrict__ Wlo,
                                                   float* __restrict__ C, int M) {
  int tid = threadIdx.x;
  int wave = tid >> 6, lane = tid & 63;
  int wr = wave >> 1, wc = wave & 1;
  int m0 = blockIdx.x * 128 + wr * 64;
  int n0 = blockIdx.y * 128 + wc * 64;
  int lr = lane & 15;
  int kg = (lane >> 4) * 8;     // same (lane,reg)->k map for A and B: any consistent bijection is valid
  f32x4 acc[4][4];
#pragma unroll
  for (int i = 0; i < 4; ++i)
#pragma unroll
    for (int j = 0; j < 4; ++j) { acc[i][j].x = 0.f; acc[i][j].y = 0.f; acc[i][j].z = 0.f; acc[i][j].w = 0.f; }

#pragma unroll 2
  for (int k0 = 0; k0 < HID; k0 += 32) {
    bf16x8 ah[4], al[4], bh[4], bl[4];
#pragma unroll
    for (int i = 0; i < 4; ++i) {
      int row = m0 + i * 16 + lr;
      if (row >= M) row = M - 1;    // M%16==0 -> dead fragments only; C-write guarded
      const ushort* pa = Ahi + (size_t)row * HID + k0 + kg;
      const ushort* pl = Alo + (size_t)row * HID + k0 + kg;
      ah[i] = *(const bf16x8*)pa;
      al[i] = *(const bf16x8*)pl;
    }
#pragma unroll
    for (int j = 0; j < 4; ++j) {
      int col = n0 + j * 16 + lr;
      bh[j] = *(const bf16x8*)(Whi + (size_t)col * HID + k0 + kg);
      bl[j] = *(const bf16x8*)(Wlo + (size_t)col * HID + k0 + kg);
    }
#pragma unroll
    for (int i = 0; i < 4; ++i)
#pragma unroll
      for (int j = 0; j < 4; ++j) {
        acc[i][j] = __builtin_amdgcn_mfma_f32_16x16x32_bf16(ah[i], bh[j], acc[i][j], 0, 0, 0);
        acc[i][j] = __builtin_amdgcn_mfma_f32_16x16x32_bf16(ah[i], bl[j], acc[i][j], 0, 0, 0);
        acc[i][j] = __builtin_amdgcn_mfma_f32_16x16x32_bf16(al[i], bh[j], acc[i][j], 0, 0, 0);
      }
  }
  // C/D: col = lane&15, row = (lane>>4)*4 + reg   [HW-verified m89/m91]
  int rb = (lane >> 4) * 2;  // dummy to avoid recompute; actual below
  (void)rb;
#pragma unroll
  for (int i = 0; i < 4; ++i) {
#pragma unroll
    for (int r = 0; r < 4; ++r) {
      int row = m0 + i * 16 + (lane >> 4) * 4 + r;
      if (row < M) {
        float* cp = C + (size_t)row * HID + n0 + (lane & 15);
        cp[0]  = acc[i][0][r];
        cp[16] = acc[i][1][r];
        cp[32] = acc[i][2][r];
        cp[48] = acc[i][3][r];
      }
    }
  }
}

// ---------------- aggregate: one wave per dst node -> bf16 hi/lo ----------------
__global__ __launch_bounds__(256) void k_aggregate(const float* __restrict__ T, const float* __restrict__ dinv,
                                                   const int* __restrict__ row_start, const int* __restrict__ csr_src,
                                                   const float* __restrict__ bias,
                                                   ushort* __restrict__ Ahi, ushort* __restrict__ Alo) {
  int wid = blockIdx.x * 4 + (threadIdx.x >> 6);
  int lane = threadIdx.x & 63;
  if (wid >= NN) return;
  float di = dinv[wid];
  int s = row_start[wid], e = row_start[wid + 1];
  float4 acc = make_float4(0.f, 0.f, 0.f, 0.f);
  for (int t = s; t < e; ++t) {
    int src = csr_src[t];
    float c = dinv[src] * di;
    float4 v = ((const float4*)(T + (size_t)src * HID))[lane];
    acc.x = fmaf(v.x, c, acc.x); acc.y = fmaf(v.y, c, acc.y);
    acc.z = fmaf(v.z, c, acc.z); acc.w = fmaf(v.w, c, acc.w);
  }
  float4 v = ((const float4*)(T + (size_t)wid * HID))[lane];
  float sc = di * di;
  float4 bb = ((const float4*)bias)[lane];
  acc.x = fmaf(v.x, sc, acc.x) + bb.x;
  acc.y = fmaf(v.y, sc, acc.y) + bb.y;
  acc.z = fmaf(v.z, sc, acc.z) + bb.z;
  acc.w = fmaf(v.w, sc, acc.w) + bb.w;
  ushort4 h4, l4;
  splitbf(acc.x, h4.x, l4.x); splitbf(acc.y, h4.y, l4.y);
  splitbf(acc.z, h4.z, l4.z); splitbf(acc.w, h4.w, l4.w);
  ((ushort4*)(Ahi + (size_t)wid * HID))[lane] = h4;
  ((ushort4*)(Alo + (size_t)wid * HID))[lane] = l4;
}

// ---------------- GraphNorm (+ReLU, + pool on last layer), in-place on hi/lo ----------------
__global__ __launch_bounds__(256) void k_gnorm(ushort* __restrict__ Ahi, ushort* __restrict__ Alo,
                                               const int* __restrict__ gstart,
                                               const float* __restrict__ alpha, const float* __restrict__ gamma,
                                               const float* __restrict__ beta, float* __restrict__ pooled,
                                               int last) {
  int g = blockIdx.x, c = threadIdx.x;
  int s = gstart[g], e = gstart[g + 1];
  int n = e - s;
  float cnt = (float)(n > 1 ? n : 1);
  float s1 = 0.f, s2 = 0.f;
  for (int i = s; i < e; ++i) {
    float v = joinbf(Ahi[(size_t)i * HID + c], Alo[(size_t)i * HID + c]);
    s1 += v; s2 = fmaf(v, v, s2);
  }
  float mean = s1 / cnt;
  float am = alpha[c] * mean;
  float var = s2 / cnt - 2.f * am * mean + am * am;   // E[(h-am)^2]
  float rs = rsqrtf(var + EPSV);
  float ga = gamma[c], be = beta[c];
  if (last) {
    float pool = 0.f;
    for (int i = s; i < e; ++i) {
      float v = joinbf(Ahi[(size_t)i * HID + c], Alo[(size_t)i * HID + c]);
      pool += fmaxf((v - am) * rs * ga + be, 0.f);
    }
    pooled[g * HID + c] = pool;
  } else {
    for (int i = s; i < e; ++i) {
      float v = joinbf(Ahi[(size_t)i * HID + c], Alo[(size_t)i * HID + c]);
      float o = fmaxf((v - am) * rs * ga + be, 0.f);
      ushort h, l; splitbf(o, h, l);
      Ahi[(size_t)i * HID + c] = h;
      Alo[(size_t)i * HID + c] = l;
    }
  }
}

// ---------------- W1 transpose ----------------
__global__ void k_transpose(const float* __restrict__ W, float* __restrict__ Wt) {
  __shared__ float tile[32][33];
  int bx = blockIdx.x, by = blockIdx.y;
  int tx = threadIdx.x, ty = threadIdx.y;   // 32 x 8
  for (int r = 0; r < 32; r += 8)
    tile[ty + r][tx] = W[(size_t)(by * 32 + ty + r) * HID + bx * 32 + tx];
  __syncthreads();
  for (int r = 0; r < 32; r += 8)
    Wt[(size_t)(bx * 32 + ty + r) * HID + by * 32 + tx] = tile[tx][ty + r];
}

// ---------------- head ----------------
__global__ __launch_bounds__(256) void k_head(const float* __restrict__ pooled, const float* __restrict__ W1t,
                                              const float* __restrict__ b1, const float* __restrict__ Wout,
                                              const float* __restrict__ bout, float* __restrict__ out) {
  int g = blockIdx.x, t = threadIdx.x;
  __shared__ float gv[HID];
  __shared__ float red[HID];
  gv[t] = pooled[g * HID + t];
  __syncthreads();
  float acc = b1[t];
  for (int k = 0; k < HID; ++k) acc = fmaf(gv[k], W1t[k * HID + t], acc);
  float h = fmaxf(acc, 0.f);
  red[t] = h * Wout[t];
  __syncthreads();
  for (int off = 128; off > 0; off >>= 1) {
    if (t < off) red[t] += red[t + off];
    __syncthreads();
  }
  if (t == 0) out[g] = 1.f / (1.f + expf(-(red[0] + bout[0])));
}

// ---------------- launch ----------------
extern "C" void kernel_launch(void* const* d_in, const int* in_sizes, int n_in,
                              void* d_out, int out_size, void* d_ws, size_t ws_size,
                              hipStream_t stream) {
  const float* x          = (const float*)d_in[0];
  const int*   edge_index = (const int*)d_in[1];
  const int*   batch      = (const int*)d_in[2];
  const float* lin0_W     = (const float*)d_in[3];
  const float* lin0_b     = (const float*)d_in[4];
  const float* conv_W     = (const float*)d_in[5];
  const float* conv_b     = (const float*)d_in[6];
  const float* n_alpha    = (const float*)d_in[7];
  const float* n_gamma    = (const float*)d_in[8];
  const float* n_beta     = (const float*)d_in[9];
  const float* lin1_W     = (const float*)d_in[10];
  const float* lin1_b     = (const float*)d_in[11];
  const float* out_W      = (const float*)d_in[12];
  const float* out_b      = (const float*)d_in[13];
  float* out = (float*)d_out;

  char* ws = (char*)d_ws;
  size_t off = 0;
  auto nxt = [&](size_t bytes) { size_t o = off; off += (bytes + 255) & ~(size_t)255; return o; };
  ushort* Ahi    = (ushort*)(ws + nxt((size_t)NN * HID * 2));
  ushort* Alo    = (ushort*)(ws + nxt((size_t)NN * HID * 2));
  float*  Tbuf   = (float*) (ws + nxt((size_t)NN * HID * 4));
  float*  dinv   = (float*) (ws + nxt((size_t)NN * 4));
  int*    deg    = (int*)   (ws + nxt((size_t)NN * 4));
  int*    rstart = (int*)   (ws + nxt((size_t)(NN + 1) * 4));
  int*    csrsrc = (int*)   (ws + nxt((size_t)NE * 4));
  int*    gstart = (int*)   (ws + nxt((size_t)(NG + 1) * 4));
  char*   poolbase = ws + nxt((size_t)NG * HID * 4);     // 2,048,000 B block, sub-carved:
  float*  pooled = (float*)poolbase;                      //   written only at layer-3 gnorm
  int*    pos    = (int*)(poolbase);                      //   [0, 400000) dead after csr_fill
  ushort* Whi    = (ushort*)(poolbase + 400384);          //   [400384, 793600) dead after last gemm
  ushort* Wlo    = (ushort*)(poolbase + 793600);          //   [793600, 1186816) dead after last gemm
  float*  W1t    = (float*) (ws + nxt((size_t)HID * HID * 4));
  int*    part   = (int*)   (ws + nxt((size_t)NCHUNK * 4));
  (void)ws_size; (void)in_sizes; (void)n_in; (void)out_size;

  hipMemsetAsync(deg, 0, (size_t)NN * 4, stream);
  k_deg<<<(NE + 255) / 256, 256, 0, stream>>>(edge_index, deg);
  k_dinv<<<(NN + 255) / 256, 256, 0, stream>>>(deg, dinv);
  k_scanA<<<NCHUNK, 256, 0, stream>>>(deg, part);
  k_scanB<<<1, 128, 0, stream>>>(part);
  k_scanC<<<NCHUNK, 256, 0, stream>>>(deg, part, rstart, pos);
  k_csr_fill<<<(NE + 255) / 256, 256, 0, stream>>>(edge_index, pos, csrsrc);
  k_gstart<<<(NN + 255) / 256, 256, 0, stream>>>(batch, gstart);
  k_wcvt<<<(3 * HID * HID + 255) / 256, 256, 0, stream>>>(conv_W, Whi, Wlo, 3 * HID * HID);
  k_lin0<<<NN / 32, 256, 0, stream>>>(x, lin0_W, lin0_b, Ahi, Alo);
  k_transpose<<<dim3(8, 8), dim3(32, 8), 0, stream>>>(lin1_W, W1t);

  for (int l = 0; l < 3; ++l) {
    k_gemm_mfma<<<dim3((NN + 127) / 128, HID / 128), 256, 0, stream>>>(
        Ahi, Alo, Whi + (size_t)l * HID * HID, Wlo + (size_t)l * HID * HID, Tbuf, NN);
    k_aggregate<<<(NN + 3) / 4, 256, 0, stream>>>(Tbuf, dinv, rstart, csrsrc, conv_b + l * HID, Ahi, Alo);
    k_gnorm<<<NG, 256, 0, stream>>>(Ahi, Alo, gstart, n_alpha + l * HID, n_gamma + l * HID, n_beta + l * HID,
                                    pooled, l == 2 ? 1 : 0);
  }
  k_head<<<NG, 256, 0, stream>>>(pooled, W1t, lin1_b, out_W, out_b, out);
}

// Round 3
// 866.499 us; speedup vs baseline: 1.2988x; 1.0476x over previous
//
#include <hip/hip_runtime.h>
#include <math.h>

#define NN 100000   // nodes
#define NE 300000   // edges
#define NG 2000     // graphs
#define HID 256
#define CIN 59
#define KPAD 64     // CIN padded to MFMA K
#define EPSV 1e-5f

#define SCAN_CHUNK 1024
#define NCHUNK ((NN + SCAN_CHUNK - 1) / SCAN_CHUNK)   // 98

typedef __attribute__((ext_vector_type(8))) short bf16x8;   // 8 bf16 (4 VGPRs)
typedef __attribute__((ext_vector_type(4))) float f32x4;

// ---------- f32 -> (bf16 hi, bf16 lo) split, round-to-nearest ----------
__device__ inline void splitbf(float x, ushort& hi, ushort& lo) {
  union { float f; unsigned u; } a; a.f = x;
  unsigned r = a.u + 0x7FFFu + ((a.u >> 16) & 1u);
  hi = (ushort)(r >> 16);
  union { unsigned u; float f; } h; h.u = (unsigned)hi << 16;
  union { float f; unsigned u; } d; d.f = x - h.f;
  unsigned r2 = d.u + 0x7FFFu + ((d.u >> 16) & 1u);
  lo = (ushort)(r2 >> 16);
}
__device__ inline float joinbf(ushort hi, ushort lo) {
  union { unsigned u; float f; } a, b;
  a.u = (unsigned)hi << 16; b.u = (unsigned)lo << 16;
  return a.f + b.f;
}

// ---------------- degree / CSR build ----------------

__global__ __launch_bounds__(256) void k_deg(const int* __restrict__ ei, int* __restrict__ deg) {
  int e = blockIdx.x * 256 + threadIdx.x;
  if (e < NE) atomicAdd(&deg[ei[NE + e]], 1);   // dst = ei[1][e]
}

__global__ __launch_bounds__(256) void k_dinv(const int* __restrict__ deg, float* __restrict__ dinv) {
  int i = blockIdx.x * 256 + threadIdx.x;
  if (i < NN) dinv[i] = rsqrtf((float)deg[i] + 1.0f);  // +1 self loop
}

__global__ __launch_bounds__(256) void k_scanA(const int* __restrict__ deg, int* __restrict__ part) {
  __shared__ int sm[256];
  int b = blockIdx.x, t = threadIdx.x;
  int base = b * SCAN_CHUNK + t * 4;
  int s = 0;
#pragma unroll
  for (int j = 0; j < 4; ++j) { int idx = base + j; if (idx < NN) s += deg[idx]; }
  sm[t] = s; __syncthreads();
  for (int off = 128; off > 0; off >>= 1) {
    if (t < off) sm[t] += sm[t + off];
    __syncthreads();
  }
  if (t == 0) part[b] = sm[0];
}

__global__ void k_scanB(int* __restrict__ part) {  // 128 threads
  __shared__ int sm[128];
  int t = threadIdx.x;
  int v = (t < NCHUNK) ? part[t] : 0;
  sm[t] = v; __syncthreads();
  for (int off = 1; off < 128; off <<= 1) {
    int x = (t >= off) ? sm[t - off] : 0;
    __syncthreads();
    sm[t] += x;
    __syncthreads();
  }
  if (t < NCHUNK) part[t] = sm[t] - v;  // exclusive
}

__global__ __launch_bounds__(256) void k_scanC(const int* __restrict__ deg, const int* __restrict__ part,
                                               int* __restrict__ row_start, int* __restrict__ pos) {
  __shared__ int sm[256];
  int b = blockIdx.x, t = threadIdx.x;
  int base = b * SCAN_CHUNK + t * 4;
  int v[4]; int s = 0;
#pragma unroll
  for (int j = 0; j < 4; ++j) { int idx = base + j; v[j] = (idx < NN) ? deg[idx] : 0; s += v[j]; }
  sm[t] = s; __syncthreads();
  for (int off = 1; off < 256; off <<= 1) {
    int x = (t >= off) ? sm[t - off] : 0;
    __syncthreads();
    sm[t] += x;
    __syncthreads();
  }
  int excl = sm[t] - s + part[b];
#pragma unroll
  for (int j = 0; j < 4; ++j) {
    int idx = base + j;
    if (idx < NN) { row_start[idx] = excl; pos[idx] = excl; excl += v[j]; }
  }
  if (b == 0 && t == 0) row_start[NN] = NE;
}

__global__ __launch_bounds__(256) void k_csr_fill(const int* __restrict__ ei, int* __restrict__ pos,
                                                  int* __restrict__ csr_src) {
  int e = blockIdx.x * 256 + threadIdx.x;
  if (e >= NE) return;
  int d = ei[NE + e];
  int slot = atomicAdd(&pos[d], 1);
  csr_src[slot] = ei[e];
}

__global__ __launch_bounds__(256) void k_gstart(const int* __restrict__ batch, int* __restrict__ gstart) {
  int i = blockIdx.x * 256 + threadIdx.x;
  if (i >= NN) return;
  int b = batch[i];
  int pb = (i == 0) ? -1 : batch[i - 1];
  for (int g = pb + 1; g <= b; ++g) gstart[g] = i;
  if (i == NN - 1) {
    for (int g = b + 1; g <= NG; ++g) gstart[g] = NN;
  }
}

// ---------------- conv_W -> bf16 hi/lo ----------------
__global__ __launch_bounds__(256) void k_wcvt(const float* __restrict__ W, ushort* __restrict__ Whi,
                                              ushort* __restrict__ Wlo, int n) {
  int i = blockIdx.x * 256 + threadIdx.x;
  if (i >= n) return;
  ushort h, l; splitbf(W[i], h, l);
  Whi[i] = h; Wlo[i] = l;
}

// ---------------- lin0_W [256][59] -> padded [256][64] hi/lo ----------------
__global__ __launch_bounds__(256) void k_w0cvt(const float* __restrict__ W, ushort* __restrict__ Whi,
                                               ushort* __restrict__ Wlo) {
  int i = blockIdx.x * 256 + threadIdx.x;   // over 256*64
  int row = i >> 6, k = i & 63;
  float v = (k < CIN) ? W[row * CIN + k] : 0.f;
  ushort h, l; splitbf(v, h, l);
  Whi[i] = h; Wlo[i] = l;
}

// ---------------- x [N][59] -> padded [N][64] hi/lo, wave per node ----------------
__global__ __launch_bounds__(256) void k_xcvt(const float* __restrict__ x, ushort* __restrict__ Xhi,
                                              ushort* __restrict__ Xlo) {
  int wid = blockIdx.x * 4 + (threadIdx.x >> 6);
  int lane = threadIdx.x & 63;
  if (wid >= NN) return;
  float v = (lane < CIN) ? x[(size_t)wid * CIN + lane] : 0.f;
  ushort h, l; splitbf(v, h, l);
  Xhi[(size_t)wid * KPAD + lane] = h;
  Xlo[(size_t)wid * KPAD + lane] = l;
}

// ---------------- lin0 via MFMA: H = elu(X @ W0^T + b0) -> hi/lo ----------------
// tile 64 rows x 256 cols, 4 waves (each 64x64), K = 64 (2 k-steps).
__global__ __launch_bounds__(256) void k_lin0g(const ushort* __restrict__ Xhi, const ushort* __restrict__ Xlo,
                                               const ushort* __restrict__ Whi, const ushort* __restrict__ Wlo,
                                               const float* __restrict__ bias,
                                               ushort* __restrict__ Ahi, ushort* __restrict__ Alo) {
  int tid = threadIdx.x;
  int wave = tid >> 6, lane = tid & 63;
  int m0 = blockIdx.x * 64;
  int n0 = wave * 64;
  int lr = lane & 15;
  int kg = (lane >> 4) * 8;
  f32x4 acc[4][4];
#pragma unroll
  for (int i = 0; i < 4; ++i)
#pragma unroll
    for (int j = 0; j < 4; ++j) { acc[i][j].x = 0.f; acc[i][j].y = 0.f; acc[i][j].z = 0.f; acc[i][j].w = 0.f; }

#pragma unroll
  for (int k0 = 0; k0 < KPAD; k0 += 32) {
    bf16x8 ah[4], al[4], bh[4], bl[4];
#pragma unroll
    for (int i = 0; i < 4; ++i) {
      int row = m0 + i * 16 + lr;
      if (row >= NN) row = NN - 1;
      ah[i] = *(const bf16x8*)(Xhi + (size_t)row * KPAD + k0 + kg);
      al[i] = *(const bf16x8*)(Xlo + (size_t)row * KPAD + k0 + kg);
    }
#pragma unroll
    for (int j = 0; j < 4; ++j) {
      int col = n0 + j * 16 + lr;
      bh[j] = *(const bf16x8*)(Whi + (size_t)col * KPAD + k0 + kg);
      bl[j] = *(const bf16x8*)(Wlo + (size_t)col * KPAD + k0 + kg);
    }
#pragma unroll
    for (int i = 0; i < 4; ++i)
#pragma unroll
      for (int j = 0; j < 4; ++j) {
        acc[i][j] = __builtin_amdgcn_mfma_f32_16x16x32_bf16(ah[i], bh[j], acc[i][j], 0, 0, 0);
        acc[i][j] = __builtin_amdgcn_mfma_f32_16x16x32_bf16(ah[i], bl[j], acc[i][j], 0, 0, 0);
        acc[i][j] = __builtin_amdgcn_mfma_f32_16x16x32_bf16(al[i], bh[j], acc[i][j], 0, 0, 0);
      }
  }
  // C/D: col = lane&15, row = (lane>>4)*4 + reg
#pragma unroll
  for (int i = 0; i < 4; ++i) {
#pragma unroll
    for (int r = 0; r < 4; ++r) {
      int row = m0 + i * 16 + (lane >> 4) * 4 + r;
      if (row < NN) {
#pragma unroll
        for (int j = 0; j < 4; ++j) {
          int col = n0 + j * 16 + lr;
          float v = acc[i][j][r] + bias[col];
          v = v > 0.f ? v : expm1f(v);           // ELU
          ushort h, l; splitbf(v, h, l);
          Ahi[(size_t)row * HID + col] = h;
          Alo[(size_t)row * HID + col] = l;
        }
      }
    }
  }
}

// ---------------- MFMA split-bf16 GEMM: C = A @ W^T ----------------
// block tile 128x256 (full N in one pass -> A read once), 8 waves (2x4), wave 64x64.
__global__ __launch_bounds__(512) void k_gemm_mfma(const ushort* __restrict__ Ahi, const ushort* __restrict__ Alo,
                                                   const ushort* __restrict__ Whi, const ushort* __restrict__ Wlo,
                                                   float* __restrict__ C, int M) {
  int tid = threadIdx.x;
  int wave = tid >> 6, lane = tid & 63;
  int wr = wave >> 2, wc = wave & 3;
  int m0 = blockIdx.x * 128 + wr * 64;
  int n0 = wc * 64;
  int lr = lane & 15;
  int kg = (lane >> 4) * 8;     // same (lane,reg)->k map for A and B
  f32x4 acc[4][4];
#pragma unroll
  for (int i = 0; i < 4; ++i)
#pragma unroll
    for (int j = 0; j < 4; ++j) { acc[i][j].x = 0.f; acc[i][j].y = 0.f; acc[i][j].z = 0.f; acc[i][j].w = 0.f; }

#pragma unroll 2
  for (int k0 = 0; k0 < HID; k0 += 32) {
    bf16x8 ah[4], al[4], bh[4], bl[4];
#pragma unroll
    for (int i = 0; i < 4; ++i) {
      int row = m0 + i * 16 + lr;
      if (row >= M) row = M - 1;    // M%16==0 -> dead fragments only; C-write guarded
      ah[i] = *(const bf16x8*)(Ahi + (size_t)row * HID + k0 + kg);
      al[i] = *(const bf16x8*)(Alo + (size_t)row * HID + k0 + kg);
    }
#pragma unroll
    for (int j = 0; j < 4; ++j) {
      int col = n0 + j * 16 + lr;
      bh[j] = *(const bf16x8*)(Whi + (size_t)col * HID + k0 + kg);
      bl[j] = *(const bf16x8*)(Wlo + (size_t)col * HID + k0 + kg);
    }
#pragma unroll
    for (int i = 0; i < 4; ++i)
#pragma unroll
      for (int j = 0; j < 4; ++j) {
        acc[i][j] = __builtin_amdgcn_mfma_f32_16x16x32_bf16(ah[i], bh[j], acc[i][j], 0, 0, 0);
        acc[i][j] = __builtin_amdgcn_mfma_f32_16x16x32_bf16(ah[i], bl[j], acc[i][j], 0, 0, 0);
        acc[i][j] = __builtin_amdgcn_mfma_f32_16x16x32_bf16(al[i], bh[j], acc[i][j], 0, 0, 0);
      }
  }
  // C/D: col = lane&15, row = (lane>>4)*4 + reg
#pragma unroll
  for (int i = 0; i < 4; ++i) {
#pragma unroll
    for (int r = 0; r < 4; ++r) {
      int row = m0 + i * 16 + (lane >> 4) * 4 + r;
      if (row < M) {
        float* cp = C + (size_t)row * HID + n0 + lr;
        cp[0]  = acc[i][0][r];
        cp[16] = acc[i][1][r];
        cp[32] = acc[i][2][r];
        cp[48] = acc[i][3][r];
      }
    }
  }
}

// ---------------- aggregate: one wave per dst node -> bf16 hi/lo ----------------
__global__ __launch_bounds__(256) void k_aggregate(const float* __restrict__ T, const float* __restrict__ dinv,
                                                   const int* __restrict__ row_start, const int* __restrict__ csr_src,
                                                   const float* __restrict__ bias,
                                                   ushort* __restrict__ Ahi, ushort* __restrict__ Alo) {
  int wid = blockIdx.x * 4 + (threadIdx.x >> 6);
  int lane = threadIdx.x & 63;
  if (wid >= NN) return;
  float di = dinv[wid];
  int s = row_start[wid], e = row_start[wid + 1];
  float4 acc = make_float4(0.f, 0.f, 0.f, 0.f);
  for (int t = s; t < e; ++t) {
    int src = csr_src[t];
    float c = dinv[src] * di;
    float4 v = ((const float4*)(T + (size_t)src * HID))[lane];
    acc.x = fmaf(v.x, c, acc.x); acc.y = fmaf(v.y, c, acc.y);
    acc.z = fmaf(v.z, c, acc.z); acc.w = fmaf(v.w, c, acc.w);
  }
  float4 v = ((const float4*)(T + (size_t)wid * HID))[lane];
  float sc = di * di;
  float4 bb = ((const float4*)bias)[lane];
  acc.x = fmaf(v.x, sc, acc.x) + bb.x;
  acc.y = fmaf(v.y, sc, acc.y) + bb.y;
  acc.z = fmaf(v.z, sc, acc.z) + bb.z;
  acc.w = fmaf(v.w, sc, acc.w) + bb.w;
  ushort4 h4, l4;
  splitbf(acc.x, h4.x, l4.x); splitbf(acc.y, h4.y, l4.y);
  splitbf(acc.z, h4.z, l4.z); splitbf(acc.w, h4.w, l4.w);
  ((ushort4*)(Ahi + (size_t)wid * HID))[lane] = h4;
  ((ushort4*)(Alo + (size_t)wid * HID))[lane] = l4;
}

// ---------------- GraphNorm (+ReLU, + pool on last layer), in-place on hi/lo ----------------
// block = 256 threads = 4 row-chunks x 64 channel-groups (4 ch each, ushort4 loads)
__global__ __launch_bounds__(256) void k_gnorm(ushort* __restrict__ Ahi, ushort* __restrict__ Alo,
                                               const int* __restrict__ gstart,
                                               const float* __restrict__ alpha, const float* __restrict__ gamma,
                                               const float* __restrict__ beta, float* __restrict__ pooled,
                                               int last) {
  __shared__ float4 smA[4][64];
  __shared__ float4 smB[4][64];
  int g = blockIdx.x;
  int r = threadIdx.x >> 6;        // 0..3
  int cg = threadIdx.x & 63;       // channel group
  int c0 = cg * 4;
  int s = gstart[g], e = gstart[g + 1];
  int n = e - s;
  float cnt = (float)(n > 1 ? n : 1);
  float s1[4] = {0.f, 0.f, 0.f, 0.f}, s2[4] = {0.f, 0.f, 0.f, 0.f};
  for (int i = s + r; i < e; i += 4) {
    ushort4 h = *(const ushort4*)(Ahi + (size_t)i * HID + c0);
    ushort4 l = *(const ushort4*)(Alo + (size_t)i * HID + c0);
    float v0 = joinbf(h.x, l.x), v1 = joinbf(h.y, l.y), v2 = joinbf(h.z, l.z), v3 = joinbf(h.w, l.w);
    s1[0] += v0; s2[0] = fmaf(v0, v0, s2[0]);
    s1[1] += v1; s2[1] = fmaf(v1, v1, s2[1]);
    s1[2] += v2; s2[2] = fmaf(v2, v2, s2[2]);
    s1[3] += v3; s2[3] = fmaf(v3, v3, s2[3]);
  }
  smA[r][cg] = make_float4(s1[0], s1[1], s1[2], s1[3]);
  smB[r][cg] = make_float4(s2[0], s2[1], s2[2], s2[3]);
  __syncthreads();
  float4 a0 = smA[0][cg], a1 = smA[1][cg], a2 = smA[2][cg], a3 = smA[3][cg];
  float4 b0 = smB[0][cg], b1 = smB[1][cg], b2 = smB[2][cg], b3 = smB[3][cg];
  float t1[4] = {a0.x + a1.x + a2.x + a3.x, a0.y + a1.y + a2.y + a3.y,
                 a0.z + a1.z + a2.z + a3.z, a0.w + a1.w + a2.w + a3.w};
  float t2[4] = {b0.x + b1.x + b2.x + b3.x, b0.y + b1.y + b2.y + b3.y,
                 b0.z + b1.z + b2.z + b3.z, b0.w + b1.w + b2.w + b3.w};
  float4 al4 = *(const float4*)(alpha + c0);
  float4 ga4 = *(const float4*)(gamma + c0);
  float4 be4 = *(const float4*)(beta + c0);
  float am[4], rs[4], be[4];
  float alv[4] = {al4.x, al4.y, al4.z, al4.w};
  float gav[4] = {ga4.x, ga4.y, ga4.z, ga4.w};
  float bev[4] = {be4.x, be4.y, be4.z, be4.w};
#pragma unroll
  for (int j = 0; j < 4; ++j) {
    float mean = t1[j] / cnt;
    float a = alv[j] * mean;
    float var = t2[j] / cnt - 2.f * a * mean + a * a;
    am[j] = a;
    rs[j] = rsqrtf(var + EPSV) * gav[j];
    be[j] = bev[j];
  }
  if (last) {
    float p[4] = {0.f, 0.f, 0.f, 0.f};
    for (int i = s + r; i < e; i += 4) {
      ushort4 h = *(const ushort4*)(Ahi + (size_t)i * HID + c0);
      ushort4 l = *(const ushort4*)(Alo + (size_t)i * HID + c0);
      float v[4] = {joinbf(h.x, l.x), joinbf(h.y, l.y), joinbf(h.z, l.z), joinbf(h.w, l.w)};
#pragma unroll
      for (int j = 0; j < 4; ++j) p[j] += fmaxf((v[j] - am[j]) * rs[j] + be[j], 0.f);
    }
    __syncthreads();   // WAR on smA
    smA[r][cg] = make_float4(p[0], p[1], p[2], p[3]);
    __syncthreads();
    if (r == 0) {
      float4 p0 = smA[0][cg], p1 = smA[1][cg], p2 = smA[2][cg], p3 = smA[3][cg];
      float4 o = make_float4(p0.x + p1.x + p2.x + p3.x, p0.y + p1.y + p2.y + p3.y,
                             p0.z + p1.z + p2.z + p3.z, p0.w + p1.w + p2.w + p3.w);
      *(float4*)(pooled + g * HID + c0) = o;
    }
  } else {
    for (int i = s + r; i < e; i += 4) {
      ushort4 h = *(const ushort4*)(Ahi + (size_t)i * HID + c0);
      ushort4 l = *(const ushort4*)(Alo + (size_t)i * HID + c0);
      float v[4] = {joinbf(h.x, l.x), joinbf(h.y, l.y), joinbf(h.z, l.z), joinbf(h.w, l.w)};
      ushort4 ho, lo4;
      float o0 = fmaxf((v[0] - am[0]) * rs[0] + be[0], 0.f);
      float o1 = fmaxf((v[1] - am[1]) * rs[1] + be[1], 0.f);
      float o2 = fmaxf((v[2] - am[2]) * rs[2] + be[2], 0.f);
      float o3 = fmaxf((v[3] - am[3]) * rs[3] + be[3], 0.f);
      splitbf(o0, ho.x, lo4.x); splitbf(o1, ho.y, lo4.y);
      splitbf(o2, ho.z, lo4.z); splitbf(o3, ho.w, lo4.w);
      *(ushort4*)(Ahi + (size_t)i * HID + c0) = ho;
      *(ushort4*)(Alo + (size_t)i * HID + c0) = lo4;
    }
  }
}

// ---------------- W1 transpose ----------------
__global__ void k_transpose(const float* __restrict__ W, float* __restrict__ Wt) {
  __shared__ float tile[32][33];
  int bx = blockIdx.x, by = blockIdx.y;
  int tx = threadIdx.x, ty = threadIdx.y;   // 32 x 8
  for (int r = 0; r < 32; r += 8)
    tile[ty + r][tx] = W[(size_t)(by * 32 + ty + r) * HID + bx * 32 + tx];
  __syncthreads();
  for (int r = 0; r < 32; r += 8)
    Wt[(size_t)(bx * 32 + ty + r) * HID + by * 32 + tx] = tile[tx][ty + r];
}

// ---------------- head ----------------
__global__ __launch_bounds__(256) void k_head(const float* __restrict__ pooled, const float* __restrict__ W1t,
                                              const float* __restrict__ b1, const float* __restrict__ Wout,
                                              const float* __restrict__ bout, float* __restrict__ out) {
  int g = blockIdx.x, t = threadIdx.x;
  __shared__ float gv[HID];
  __shared__ float red[HID];
  gv[t] = pooled[g * HID + t];
  __syncthreads();
  float acc = b1[t];
  for (int k = 0; k < HID; ++k) acc = fmaf(gv[k], W1t[k * HID + t], acc);
  float h = fmaxf(acc, 0.f);
  red[t] = h * Wout[t];
  __syncthreads();
  for (int off = 128; off > 0; off >>= 1) {
    if (t < off) red[t] += red[t + off];
    __syncthreads();
  }
  if (t == 0) out[g] = 1.f / (1.f + expf(-(red[0] + bout[0])));
}

// ---------------- launch ----------------
extern "C" void kernel_launch(void* const* d_in, const int* in_sizes, int n_in,
                              void* d_out, int out_size, void* d_ws, size_t ws_size,
                              hipStream_t stream) {
  const float* x          = (const float*)d_in[0];
  const int*   edge_index = (const int*)d_in[1];
  const int*   batch      = (const int*)d_in[2];
  const float* lin0_W     = (const float*)d_in[3];
  const float* lin0_b     = (const float*)d_in[4];
  const float* conv_W     = (const float*)d_in[5];
  const float* conv_b     = (const float*)d_in[6];
  const float* n_alpha    = (const float*)d_in[7];
  const float* n_gamma    = (const float*)d_in[8];
  const float* n_beta     = (const float*)d_in[9];
  const float* lin1_W     = (const float*)d_in[10];
  const float* lin1_b     = (const float*)d_in[11];
  const float* out_W      = (const float*)d_in[12];
  const float* out_b      = (const float*)d_in[13];
  float* out = (float*)d_out;

  char* ws = (char*)d_ws;
  size_t off = 0;
  auto nxt = [&](size_t bytes) { size_t o = off; off += (bytes + 255) & ~(size_t)255; return o; };
  ushort* Ahi    = (ushort*)(ws + nxt((size_t)NN * HID * 2));
  ushort* Alo    = (ushort*)(ws + nxt((size_t)NN * HID * 2));
  char*   tbase  = ws + nxt((size_t)NN * HID * 4);        // Tbuf block, sub-carved:
  float*  Tbuf   = (float*)tbase;                          //   GEMM output (layers)
  ushort* Xhi    = (ushort*)tbase;                          //   [0, 12.8MB) dead after lin0g
  ushort* Xlo    = (ushort*)(tbase + (size_t)NN * KPAD * 2);//   [12.8, 25.6MB) dead after lin0g
  float*  dinv   = (float*) (ws + nxt((size_t)NN * 4));
  int*    deg    = (int*)   (ws + nxt((size_t)NN * 4));
  int*    rstart = (int*)   (ws + nxt((size_t)(NN + 1) * 4));
  int*    csrsrc = (int*)   (ws + nxt((size_t)NE * 4));
  int*    gstart = (int*)   (ws + nxt((size_t)(NG + 1) * 4));
  char*   poolbase = ws + nxt((size_t)NG * HID * 4);       // 2,048,000 B block, sub-carved:
  float*  pooled = (float*)poolbase;                        //   written only at layer-3 gnorm
  int*    pos    = (int*)(poolbase);                        //   [0, 400000) dead after csr_fill
  ushort* Whi    = (ushort*)(poolbase + 400384);            //   dead after last gemm
  ushort* Wlo    = (ushort*)(poolbase + 793600);            //   dead after last gemm
  float*  W1t    = (float*) (ws + nxt((size_t)HID * HID * 4));
  ushort* W0hi   = (ushort*)(ws + nxt((size_t)HID * KPAD * 2));
  ushort* W0lo   = (ushort*)(ws + nxt((size_t)HID * KPAD * 2));
  int*    part   = (int*)   (ws + nxt((size_t)NCHUNK * 4));
  (void)ws_size; (void)in_sizes; (void)n_in; (void)out_size;

  hipMemsetAsync(deg, 0, (size_t)NN * 4, stream);
  k_deg<<<(NE + 255) / 256, 256, 0, stream>>>(edge_index, deg);
  k_dinv<<<(NN + 255) / 256, 256, 0, stream>>>(deg, dinv);
  k_scanA<<<NCHUNK, 256, 0, stream>>>(deg, part);
  k_scanB<<<1, 128, 0, stream>>>(part);
  k_scanC<<<NCHUNK, 256, 0, stream>>>(deg, part, rstart, pos);
  k_csr_fill<<<(NE + 255) / 256, 256, 0, stream>>>(edge_index, pos, csrsrc);
  k_gstart<<<(NN + 255) / 256, 256, 0, stream>>>(batch, gstart);
  k_wcvt<<<(3 * HID * HID + 255) / 256, 256, 0, stream>>>(conv_W, Whi, Wlo, 3 * HID * HID);
  k_w0cvt<<<(HID * KPAD) / 256, 256, 0, stream>>>(lin0_W, W0hi, W0lo);
  k_xcvt<<<(NN + 3) / 4, 256, 0, stream>>>(x, Xhi, Xlo);
  k_lin0g<<<(NN + 63) / 64, 256, 0, stream>>>(Xhi, Xlo, W0hi, W0lo, lin0_b, Ahi, Alo);
  k_transpose<<<dim3(8, 8), dim3(32, 8), 0, stream>>>(lin1_W, W1t);

  for (int l = 0; l < 3; ++l) {
    k_gemm_mfma<<<(NN + 127) / 128, 512, 0, stream>>>(
        Ahi, Alo, Whi + (size_t)l * HID * HID, Wlo + (size_t)l * HID * HID, Tbuf, NN);
    k_aggregate<<<(NN + 3) / 4, 256, 0, stream>>>(Tbuf, dinv, rstart, csrsrc, conv_b + l * HID, Ahi, Alo);
    k_gnorm<<<NG, 256, 0, stream>>>(Ahi, Alo, gstart, n_alpha + l * HID, n_gamma + l * HID, n_beta + l * HID,
                                    pooled, l == 2 ? 1 : 0);
  }
  k_head<<<NG, 256, 0, stream>>>(pooled, W1t, lin1_b, out_W, out_b, out);
}

// Round 4
// 717.207 us; speedup vs baseline: 1.5691x; 1.2082x over previous
//
#include <hip/hip_runtime.h>
#include <math.h>

#define NN 100000   // nodes
#define NE 300000   // edges
#define NG 2000     // graphs
#define HID 256
#define CIN 59
#define KPAD 64     // CIN padded to MFMA K
#define EPSV 1e-5f

#define SCAN_CHUNK 1024
#define NCHUNK ((NN + SCAN_CHUNK - 1) / SCAN_CHUNK)   // 98

typedef __attribute__((ext_vector_type(8))) short bf16x8;   // 8 bf16 (4 VGPRs)
typedef __attribute__((ext_vector_type(4))) float f32x4;

// Ahi/Alo live in a row-swizzled global layout: element (r,k) is stored at
// ushort index r*HID + (k ^ ((r&7)<<3)).  This makes a LINEAR global->LDS
// copy (global_load_lds) yield a bank-conflict-free ds_read_b128 pattern in
// the GEMM (2-way max = free).  Every producer/consumer of Ahi/Alo must use
// swzk().  XOR key is a multiple of 8 -> any aligned <=8-ushort chunk stays
// contiguous & aligned.
__device__ __forceinline__ int swzk(int row, int k) { return k ^ ((row & 7) << 3); }

// ---------- f32 -> (bf16 hi, bf16 lo) split, round-to-nearest ----------
__device__ inline void splitbf(float x, ushort& hi, ushort& lo) {
  union { float f; unsigned u; } a; a.f = x;
  unsigned r = a.u + 0x7FFFu + ((a.u >> 16) & 1u);
  hi = (ushort)(r >> 16);
  union { unsigned u; float f; } h; h.u = (unsigned)hi << 16;
  union { float f; unsigned u; } d; d.f = x - h.f;
  unsigned r2 = d.u + 0x7FFFu + ((d.u >> 16) & 1u);
  lo = (ushort)(r2 >> 16);
}
__device__ inline float joinbf(ushort hi, ushort lo) {
  union { unsigned u; float f; } a, b;
  a.u = (unsigned)hi << 16; b.u = (unsigned)lo << 16;
  return a.f + b.f;
}

__device__ __forceinline__ void gload16(const ushort* g, ushort* l) {
  __builtin_amdgcn_global_load_lds(
      (const __attribute__((address_space(1))) unsigned int*)g,
      (__attribute__((address_space(3))) unsigned int*)l, 16, 0, 0);
}

// ---------------- degree / CSR build ----------------

__global__ __launch_bounds__(256) void k_deg(const int* __restrict__ ei, int* __restrict__ deg) {
  int e = blockIdx.x * 256 + threadIdx.x;
  if (e < NE) atomicAdd(&deg[ei[NE + e]], 1);   // dst = ei[1][e]
}

__global__ __launch_bounds__(256) void k_dinv(const int* __restrict__ deg, float* __restrict__ dinv) {
  int i = blockIdx.x * 256 + threadIdx.x;
  if (i < NN) dinv[i] = rsqrtf((float)deg[i] + 1.0f);  // +1 self loop
}

__global__ __launch_bounds__(256) void k_scanA(const int* __restrict__ deg, int* __restrict__ part) {
  __shared__ int sm[256];
  int b = blockIdx.x, t = threadIdx.x;
  int base = b * SCAN_CHUNK + t * 4;
  int s = 0;
#pragma unroll
  for (int j = 0; j < 4; ++j) { int idx = base + j; if (idx < NN) s += deg[idx]; }
  sm[t] = s; __syncthreads();
  for (int off = 128; off > 0; off >>= 1) {
    if (t < off) sm[t] += sm[t + off];
    __syncthreads();
  }
  if (t == 0) part[b] = sm[0];
}

__global__ void k_scanB(int* __restrict__ part) {  // 128 threads
  __shared__ int sm[128];
  int t = threadIdx.x;
  int v = (t < NCHUNK) ? part[t] : 0;
  sm[t] = v; __syncthreads();
  for (int off = 1; off < 128; off <<= 1) {
    int x = (t >= off) ? sm[t - off] : 0;
    __syncthreads();
    sm[t] += x;
    __syncthreads();
  }
  if (t < NCHUNK) part[t] = sm[t] - v;  // exclusive
}

__global__ __launch_bounds__(256) void k_scanC(const int* __restrict__ deg, const int* __restrict__ part,
                                               int* __restrict__ row_start, int* __restrict__ pos) {
  __shared__ int sm[256];
  int b = blockIdx.x, t = threadIdx.x;
  int base = b * SCAN_CHUNK + t * 4;
  int v[4]; int s = 0;
#pragma unroll
  for (int j = 0; j < 4; ++j) { int idx = base + j; v[j] = (idx < NN) ? deg[idx] : 0; s += v[j]; }
  sm[t] = s; __syncthreads();
  for (int off = 1; off < 256; off <<= 1) {
    int x = (t >= off) ? sm[t - off] : 0;
    __syncthreads();
    sm[t] += x;
    __syncthreads();
  }
  int excl = sm[t] - s + part[b];
#pragma unroll
  for (int j = 0; j < 4; ++j) {
    int idx = base + j;
    if (idx < NN) { row_start[idx] = excl; pos[idx] = excl; excl += v[j]; }
  }
  if (b == 0 && t == 0) row_start[NN] = NE;
}

__global__ __launch_bounds__(256) void k_csr_fill(const int* __restrict__ ei, int* __restrict__ pos,
                                                  int* __restrict__ csr_src) {
  int e = blockIdx.x * 256 + threadIdx.x;
  if (e >= NE) return;
  int d = ei[NE + e];
  int slot = atomicAdd(&pos[d], 1);
  csr_src[slot] = ei[e];
}

__global__ __launch_bounds__(256) void k_gstart(const int* __restrict__ batch, int* __restrict__ gstart) {
  int i = blockIdx.x * 256 + threadIdx.x;
  if (i >= NN) return;
  int b = batch[i];
  int pb = (i == 0) ? -1 : batch[i - 1];
  for (int g = pb + 1; g <= b; ++g) gstart[g] = i;
  if (i == NN - 1) {
    for (int g = b + 1; g <= NG; ++g) gstart[g] = NN;
  }
}

// ---------------- conv_W -> bf16 hi/lo (unswizzled) ----------------
__global__ __launch_bounds__(256) void k_wcvt(const float* __restrict__ W, ushort* __restrict__ Whi,
                                              ushort* __restrict__ Wlo, int n) {
  int i = blockIdx.x * 256 + threadIdx.x;
  if (i >= n) return;
  ushort h, l; splitbf(W[i], h, l);
  Whi[i] = h; Wlo[i] = l;
}

// ---------------- lin0_W [256][59] -> padded [256][64] hi/lo ----------------
__global__ __launch_bounds__(256) void k_w0cvt(const float* __restrict__ W, ushort* __restrict__ Whi,
                                               ushort* __restrict__ Wlo) {
  int i = blockIdx.x * 256 + threadIdx.x;   // over 256*64
  int row = i >> 6, k = i & 63;
  float v = (k < CIN) ? W[row * CIN + k] : 0.f;
  ushort h, l; splitbf(v, h, l);
  Whi[i] = h; Wlo[i] = l;
}

// ---------------- x [N][59] -> padded [N][64] hi/lo, wave per node ----------------
__global__ __launch_bounds__(256) void k_xcvt(const float* __restrict__ x, ushort* __restrict__ Xhi,
                                              ushort* __restrict__ Xlo) {
  int wid = blockIdx.x * 4 + (threadIdx.x >> 6);
  int lane = threadIdx.x & 63;
  if (wid >= NN) return;
  float v = (lane < CIN) ? x[(size_t)wid * CIN + lane] : 0.f;
  ushort h, l; splitbf(v, h, l);
  Xhi[(size_t)wid * KPAD + lane] = h;
  Xlo[(size_t)wid * KPAD + lane] = l;
}

// ---------------- lin0 via MFMA: H = elu(X @ W0^T + b0) -> swizzled hi/lo ----------------
__global__ __launch_bounds__(256) void k_lin0g(const ushort* __restrict__ Xhi, const ushort* __restrict__ Xlo,
                                               const ushort* __restrict__ Whi, const ushort* __restrict__ Wlo,
                                               const float* __restrict__ bias,
                                               ushort* __restrict__ Ahi, ushort* __restrict__ Alo) {
  int tid = threadIdx.x;
  int wave = tid >> 6, lane = tid & 63;
  int m0 = blockIdx.x * 64;
  int n0 = wave * 64;
  int lr = lane & 15;
  int kg = (lane >> 4) * 8;
  f32x4 acc[4][4];
#pragma unroll
  for (int i = 0; i < 4; ++i)
#pragma unroll
    for (int j = 0; j < 4; ++j) { acc[i][j].x = 0.f; acc[i][j].y = 0.f; acc[i][j].z = 0.f; acc[i][j].w = 0.f; }

#pragma unroll
  for (int k0 = 0; k0 < KPAD; k0 += 32) {
    bf16x8 ah[4], al[4], bh[4], bl[4];
#pragma unroll
    for (int i = 0; i < 4; ++i) {
      int row = m0 + i * 16 + lr;
      if (row >= NN) row = NN - 1;
      ah[i] = *(const bf16x8*)(Xhi + (size_t)row * KPAD + k0 + kg);
      al[i] = *(const bf16x8*)(Xlo + (size_t)row * KPAD + k0 + kg);
    }
#pragma unroll
    for (int j = 0; j < 4; ++j) {
      int col = n0 + j * 16 + lr;
      bh[j] = *(const bf16x8*)(Whi + (size_t)col * KPAD + k0 + kg);
      bl[j] = *(const bf16x8*)(Wlo + (size_t)col * KPAD + k0 + kg);
    }
#pragma unroll
    for (int i = 0; i < 4; ++i)
#pragma unroll
      for (int j = 0; j < 4; ++j) {
        acc[i][j] = __builtin_amdgcn_mfma_f32_16x16x32_bf16(ah[i], bh[j], acc[i][j], 0, 0, 0);
        acc[i][j] = __builtin_amdgcn_mfma_f32_16x16x32_bf16(ah[i], bl[j], acc[i][j], 0, 0, 0);
        acc[i][j] = __builtin_amdgcn_mfma_f32_16x16x32_bf16(al[i], bh[j], acc[i][j], 0, 0, 0);
      }
  }
  // C/D: col = lane&15, row = (lane>>4)*4 + reg
#pragma unroll
  for (int i = 0; i < 4; ++i) {
#pragma unroll
    for (int r = 0; r < 4; ++r) {
      int row = m0 + i * 16 + (lane >> 4) * 4 + r;
      if (row < NN) {
#pragma unroll
        for (int j = 0; j < 4; ++j) {
          int col = n0 + j * 16 + lr;
          float v = acc[i][j][r] + bias[col];
          v = v > 0.f ? v : expm1f(v);           // ELU
          ushort h, l; splitbf(v, h, l);
          int kc = swzk(row, col);
          Ahi[(size_t)row * HID + kc] = h;
          Alo[(size_t)row * HID + kc] = l;
        }
      }
    }
  }
}

// ---------------- MFMA split-bf16 GEMM: C = A @ W^T ----------------
// BM=64, 4 waves; full-K A-tile (hi+lo, 64 KB) LDS-resident via global_load_lds.
// 2 blocks/CU (LDS-capped) -> one block computes while the other streams HBM.
#define GBM 64
__global__ __launch_bounds__(256) void k_gemm_mfma(const ushort* __restrict__ Ahi, const ushort* __restrict__ Alo,
                                                   const ushort* __restrict__ Whi, const ushort* __restrict__ Wlo,
                                                   float* __restrict__ C, int M) {
  __shared__ ushort sAhi[GBM * HID];   // 32 KB, linear copy of swizzled global
  __shared__ ushort sAlo[GBM * HID];   // 32 KB
  int tid = threadIdx.x;
  int wave = tid >> 6, lane = tid & 63;
  int m0 = blockIdx.x * GBM;
  int n0 = wave * 64;
  int lr = lane & 15;
  int q  = lane >> 4;
  int kg = q * 8;

  // ---- stage A tile: 32 segments x 1024 B per buffer, 8 per wave ----
  const ushort* gh = Ahi + (size_t)m0 * HID;
  const ushort* gl = Alo + (size_t)m0 * HID;
#pragma unroll
  for (int sgm = 0; sgm < 8; ++sgm) {
    int seg = sgm * 4 + wave;            // 0..31
    gload16(gh + seg * 512 + lane * 8, &sAhi[seg * 512]);
    gload16(gl + seg * 512 + lane * 8, &sAlo[seg * 512]);
  }
  __syncthreads();   // drains vmcnt -> LDS tile complete

  f32x4 acc[4][4];
#pragma unroll
  for (int i = 0; i < 4; ++i)
#pragma unroll
    for (int j = 0; j < 4; ++j) { acc[i][j].x = 0.f; acc[i][j].y = 0.f; acc[i][j].z = 0.f; acc[i][j].w = 0.f; }

#pragma unroll 2
  for (int k0 = 0; k0 < HID; k0 += 32) {
    bf16x8 ah[4], al[4], bh[4], bl[4];
#pragma unroll
    for (int j = 0; j < 4; ++j) {        // W from L2 (hot: 131 KB x2 per layer)
      int col = n0 + j * 16 + lr;
      bh[j] = *(const bf16x8*)(Whi + (size_t)col * HID + k0 + kg);
      bl[j] = *(const bf16x8*)(Wlo + (size_t)col * HID + k0 + kg);
    }
#pragma unroll
    for (int i = 0; i < 4; ++i) {        // A from LDS, swizzled -> 2-way max
      int row = i * 16 + lr;
      int kk = swzk(row, k0 + kg);
      ah[i] = *(const bf16x8*)&sAhi[row * HID + kk];
      al[i] = *(const bf16x8*)&sAlo[row * HID + kk];
    }
#pragma unroll
    for (int i = 0; i < 4; ++i)
#pragma unroll
      for (int j = 0; j < 4; ++j) {
        acc[i][j] = __builtin_amdgcn_mfma_f32_16x16x32_bf16(ah[i], bh[j], acc[i][j], 0, 0, 0);
        acc[i][j] = __builtin_amdgcn_mfma_f32_16x16x32_bf16(ah[i], bl[j], acc[i][j], 0, 0, 0);
        acc[i][j] = __builtin_amdgcn_mfma_f32_16x16x32_bf16(al[i], bh[j], acc[i][j], 0, 0, 0);
      }
  }
  // C/D: col = lane&15, row = (lane>>4)*4 + reg
#pragma unroll
  for (int i = 0; i < 4; ++i) {
#pragma unroll
    for (int r = 0; r < 4; ++r) {
      int row = m0 + i * 16 + q * 4 + r;
      if (row < M) {
        float* cp = C + (size_t)row * HID + n0 + lr;
        cp[0]  = acc[i][0][r];
        cp[16] = acc[i][1][r];
        cp[32] = acc[i][2][r];
        cp[48] = acc[i][3][r];
      }
    }
  }
}

// ---------------- aggregate: one wave per dst node -> swizzled bf16 hi/lo ----------------
__global__ __launch_bounds__(256) void k_aggregate(const float* __restrict__ T, const float* __restrict__ dinv,
                                                   const int* __restrict__ row_start, const int* __restrict__ csr_src,
                                                   const float* __restrict__ bias,
                                                   ushort* __restrict__ Ahi, ushort* __restrict__ Alo) {
  int wid = blockIdx.x * 4 + (threadIdx.x >> 6);
  int lane = threadIdx.x & 63;
  if (wid >= NN) return;
  float di = dinv[wid];
  int s = row_start[wid], e = row_start[wid + 1];
  float4 acc = make_float4(0.f, 0.f, 0.f, 0.f);
  for (int t = s; t < e; ++t) {
    int src = csr_src[t];
    float c = dinv[src] * di;
    float4 v = ((const float4*)(T + (size_t)src * HID))[lane];
    acc.x = fmaf(v.x, c, acc.x); acc.y = fmaf(v.y, c, acc.y);
    acc.z = fmaf(v.z, c, acc.z); acc.w = fmaf(v.w, c, acc.w);
  }
  float4 v = ((const float4*)(T + (size_t)wid * HID))[lane];
  float sc = di * di;
  float4 bb = ((const float4*)bias)[lane];
  acc.x = fmaf(v.x, sc, acc.x) + bb.x;
  acc.y = fmaf(v.y, sc, acc.y) + bb.y;
  acc.z = fmaf(v.z, sc, acc.z) + bb.z;
  acc.w = fmaf(v.w, sc, acc.w) + bb.w;
  ushort4 h4, l4;
  splitbf(acc.x, h4.x, l4.x); splitbf(acc.y, h4.y, l4.y);
  splitbf(acc.z, h4.z, l4.z); splitbf(acc.w, h4.w, l4.w);
  int kc = swzk(wid, lane * 4);
  *(ushort4*)(Ahi + (size_t)wid * HID + kc) = h4;
  *(ushort4*)(Alo + (size_t)wid * HID + kc) = l4;
}

// ---------------- GraphNorm (+ReLU, + pool on last layer), in-place on swizzled hi/lo ----------------
__global__ __launch_bounds__(256) void k_gnorm(ushort* __restrict__ Ahi, ushort* __restrict__ Alo,
                                               const int* __restrict__ gstart,
                                               const float* __restrict__ alpha, const float* __restrict__ gamma,
                                               const float* __restrict__ beta, float* __restrict__ pooled,
                                               int last) {
  __shared__ float4 smA[4][64];
  __shared__ float4 smB[4][64];
  int g = blockIdx.x;
  int r = threadIdx.x >> 6;        // 0..3
  int cg = threadIdx.x & 63;       // channel group
  int c0 = cg * 4;
  int s = gstart[g], e = gstart[g + 1];
  int n = e - s;
  float cnt = (float)(n > 1 ? n : 1);
  float s1[4] = {0.f, 0.f, 0.f, 0.f}, s2[4] = {0.f, 0.f, 0.f, 0.f};
  for (int i = s + r; i < e; i += 4) {
    int kc = swzk(i, c0);
    ushort4 h = *(const ushort4*)(Ahi + (size_t)i * HID + kc);
    ushort4 l = *(const ushort4*)(Alo + (size_t)i * HID + kc);
    float v0 = joinbf(h.x, l.x), v1 = joinbf(h.y, l.y), v2 = joinbf(h.z, l.z), v3 = joinbf(h.w, l.w);
    s1[0] += v0; s2[0] = fmaf(v0, v0, s2[0]);
    s1[1] += v1; s2[1] = fmaf(v1, v1, s2[1]);
    s1[2] += v2; s2[2] = fmaf(v2, v2, s2[2]);
    s1[3] += v3; s2[3] = fmaf(v3, v3, s2[3]);
  }
  smA[r][cg] = make_float4(s1[0], s1[1], s1[2], s1[3]);
  smB[r][cg] = make_float4(s2[0], s2[1], s2[2], s2[3]);
  __syncthreads();
  float4 a0 = smA[0][cg], a1 = smA[1][cg], a2 = smA[2][cg], a3 = smA[3][cg];
  float4 b0 = smB[0][cg], b1 = smB[1][cg], b2 = smB[2][cg], b3 = smB[3][cg];
  float t1[4] = {a0.x + a1.x + a2.x + a3.x, a0.y + a1.y + a2.y + a3.y,
                 a0.z + a1.z + a2.z + a3.z, a0.w + a1.w + a2.w + a3.w};
  float t2[4] = {b0.x + b1.x + b2.x + b3.x, b0.y + b1.y + b2.y + b3.y,
                 b0.z + b1.z + b2.z + b3.z, b0.w + b1.w + b2.w + b3.w};
  float4 al4 = *(const float4*)(alpha + c0);
  float4 ga4 = *(const float4*)(gamma + c0);
  float4 be4 = *(const float4*)(beta + c0);
  float am[4], rs[4], be[4];
  float alv[4] = {al4.x, al4.y, al4.z, al4.w};
  float gav[4] = {ga4.x, ga4.y, ga4.z, ga4.w};
  float bev[4] = {be4.x, be4.y, be4.z, be4.w};
#pragma unroll
  for (int j = 0; j < 4; ++j) {
    float mean = t1[j] / cnt;
    float a = alv[j] * mean;
    float var = t2[j] / cnt - 2.f * a * mean + a * a;
    am[j] = a;
    rs[j] = rsqrtf(var + EPSV) * gav[j];
    be[j] = bev[j];
  }
  if (last) {
    float p[4] = {0.f, 0.f, 0.f, 0.f};
    for (int i = s + r; i < e; i += 4) {
      int kc = swzk(i, c0);
      ushort4 h = *(const ushort4*)(Ahi + (size_t)i * HID + kc);
      ushort4 l = *(const ushort4*)(Alo + (size_t)i * HID + kc);
      float v[4] = {joinbf(h.x, l.x), joinbf(h.y, l.y), joinbf(h.z, l.z), joinbf(h.w, l.w)};
#pragma unroll
      for (int j = 0; j < 4; ++j) p[j] += fmaxf((v[j] - am[j]) * rs[j] + be[j], 0.f);
    }
    __syncthreads();   // WAR on smA
    smA[r][cg] = make_float4(p[0], p[1], p[2], p[3]);
    __syncthreads();
    if (r == 0) {
      float4 p0 = smA[0][cg], p1 = smA[1][cg], p2 = smA[2][cg], p3 = smA[3][cg];
      float4 o = make_float4(p0.x + p1.x + p2.x + p3.x, p0.y + p1.y + p2.y + p3.y,
                             p0.z + p1.z + p2.z + p3.z, p0.w + p1.w + p2.w + p3.w);
      *(float4*)(pooled + g * HID + c0) = o;
    }
  } else {
    for (int i = s + r; i < e; i += 4) {
      int kc = swzk(i, c0);
      ushort4 h = *(const ushort4*)(Ahi + (size_t)i * HID + kc);
      ushort4 l = *(const ushort4*)(Alo + (size_t)i * HID + kc);
      float v[4] = {joinbf(h.x, l.x), joinbf(h.y, l.y), joinbf(h.z, l.z), joinbf(h.w, l.w)};
      ushort4 ho, lo4;
      float o0 = fmaxf((v[0] - am[0]) * rs[0] + be[0], 0.f);
      float o1 = fmaxf((v[1] - am[1]) * rs[1] + be[1], 0.f);
      float o2 = fmaxf((v[2] - am[2]) * rs[2] + be[2], 0.f);
      float o3 = fmaxf((v[3] - am[3]) * rs[3] + be[3], 0.f);
      splitbf(o0, ho.x, lo4.x); splitbf(o1, ho.y, lo4.y);
      splitbf(o2, ho.z, lo4.z); splitbf(o3, ho.w, lo4.w);
      *(ushort4*)(Ahi + (size_t)i * HID + kc) = ho;
      *(ushort4*)(Alo + (size_t)i * HID + kc) = lo4;
    }
  }
}

// ---------------- W1 transpose ----------------
__global__ void k_transpose(const float* __restrict__ W, float* __restrict__ Wt) {
  __shared__ float tile[32][33];
  int bx = blockIdx.x, by = blockIdx.y;
  int tx = threadIdx.x, ty = threadIdx.y;   // 32 x 8
  for (int r = 0; r < 32; r += 8)
    tile[ty + r][tx] = W[(size_t)(by * 32 + ty + r) * HID + bx * 32 + tx];
  __syncthreads();
  for (int r = 0; r < 32; r += 8)
    Wt[(size_t)(bx * 32 + ty + r) * HID + by * 32 + tx] = tile[tx][ty + r];
}

// ---------------- head ----------------
__global__ __launch_bounds__(256) void k_head(const float* __restrict__ pooled, const float* __restrict__ W1t,
                                              const float* __restrict__ b1, const float* __restrict__ Wout,
                                              const float* __restrict__ bout, float* __restrict__ out) {
  int g = blockIdx.x, t = threadIdx.x;
  __shared__ float gv[HID];
  __shared__ float red[HID];
  gv[t] = pooled[g * HID + t];
  __syncthreads();
  float acc = b1[t];
  for (int k = 0; k < HID; ++k) acc = fmaf(gv[k], W1t[k * HID + t], acc);
  float h = fmaxf(acc, 0.f);
  red[t] = h * Wout[t];
  __syncthreads();
  for (int off = 128; off > 0; off >>= 1) {
    if (t < off) red[t] += red[t + off];
    __syncthreads();
  }
  if (t == 0) out[g] = 1.f / (1.f + expf(-(red[0] + bout[0])));
}

// ---------------- launch ----------------
extern "C" void kernel_launch(void* const* d_in, const int* in_sizes, int n_in,
                              void* d_out, int out_size, void* d_ws, size_t ws_size,
                              hipStream_t stream) {
  const float* x          = (const float*)d_in[0];
  const int*   edge_index = (const int*)d_in[1];
  const int*   batch      = (const int*)d_in[2];
  const float* lin0_W     = (const float*)d_in[3];
  const float* lin0_b     = (const float*)d_in[4];
  const float* conv_W     = (const float*)d_in[5];
  const float* conv_b     = (const float*)d_in[6];
  const float* n_alpha    = (const float*)d_in[7];
  const float* n_gamma    = (const float*)d_in[8];
  const float* n_beta     = (const float*)d_in[9];
  const float* lin1_W     = (const float*)d_in[10];
  const float* lin1_b     = (const float*)d_in[11];
  const float* out_W      = (const float*)d_in[12];
  const float* out_b      = (const float*)d_in[13];
  float* out = (float*)d_out;

  char* ws = (char*)d_ws;
  size_t off = 0;
  auto nxt = [&](size_t bytes) { size_t o = off; off += (bytes + 255) & ~(size_t)255; return o; };
  ushort* Ahi    = (ushort*)(ws + nxt((size_t)NN * HID * 2));
  ushort* Alo    = (ushort*)(ws + nxt((size_t)NN * HID * 2));
  char*   tbase  = ws + nxt((size_t)NN * HID * 4);        // Tbuf block, sub-carved:
  float*  Tbuf   = (float*)tbase;                          //   GEMM output (layers)
  ushort* Xhi    = (ushort*)tbase;                          //   [0, 12.8MB) dead after lin0g
  ushort* Xlo    = (ushort*)(tbase + (size_t)NN * KPAD * 2);//   [12.8, 25.6MB) dead after lin0g
  float*  dinv   = (float*) (ws + nxt((size_t)NN * 4));
  int*    deg    = (int*)   (ws + nxt((size_t)NN * 4));
  int*    rstart = (int*)   (ws + nxt((size_t)(NN + 1) * 4));
  int*    csrsrc = (int*)   (ws + nxt((size_t)NE * 4));
  int*    gstart = (int*)   (ws + nxt((size_t)(NG + 1) * 4));
  char*   poolbase = ws + nxt((size_t)NG * HID * 4);       // 2,048,000 B block, sub-carved:
  float*  pooled = (float*)poolbase;                        //   written only at layer-3 gnorm
  int*    pos    = (int*)(poolbase);                        //   [0, 400000) dead after csr_fill
  ushort* Whi    = (ushort*)(poolbase + 400384);            //   dead after last gemm
  ushort* Wlo    = (ushort*)(poolbase + 793600);            //   dead after last gemm
  float*  W1t    = (float*) (ws + nxt((size_t)HID * HID * 4));
  ushort* W0hi   = (ushort*)(ws + nxt((size_t)HID * KPAD * 2));
  ushort* W0lo   = (ushort*)(ws + nxt((size_t)HID * KPAD * 2));
  int*    part   = (int*)   (ws + nxt((size_t)NCHUNK * 4));
  (void)ws_size; (void)in_sizes; (void)n_in; (void)out_size;

  hipMemsetAsync(deg, 0, (size_t)NN * 4, stream);
  k_deg<<<(NE + 255) / 256, 256, 0, stream>>>(edge_index, deg);
  k_dinv<<<(NN + 255) / 256, 256, 0, stream>>>(deg, dinv);
  k_scanA<<<NCHUNK, 256, 0, stream>>>(deg, part);
  k_scanB<<<1, 128, 0, stream>>>(part);
  k_scanC<<<NCHUNK, 256, 0, stream>>>(deg, part, rstart, pos);
  k_csr_fill<<<(NE + 255) / 256, 256, 0, stream>>>(edge_index, pos, csrsrc);
  k_gstart<<<(NN + 255) / 256, 256, 0, stream>>>(batch, gstart);
  k_wcvt<<<(3 * HID * HID + 255) / 256, 256, 0, stream>>>(conv_W, Whi, Wlo, 3 * HID * HID);
  k_w0cvt<<<(HID * KPAD) / 256, 256, 0, stream>>>(lin0_W, W0hi, W0lo);
  k_xcvt<<<(NN + 3) / 4, 256, 0, stream>>>(x, Xhi, Xlo);
  k_lin0g<<<(NN + 63) / 64, 256, 0, stream>>>(Xhi, Xlo, W0hi, W0lo, lin0_b, Ahi, Alo);
  k_transpose<<<dim3(8, 8), dim3(32, 8), 0, stream>>>(lin1_W, W1t);

  for (int l = 0; l < 3; ++l) {
    k_gemm_mfma<<<(NN + GBM - 1) / GBM, 256, 0, stream>>>(
        Ahi, Alo, Whi + (size_t)l * HID * HID, Wlo + (size_t)l * HID * HID, Tbuf, NN);
    k_aggregate<<<(NN + 3) / 4, 256, 0, stream>>>(Tbuf, dinv, rstart, csrsrc, conv_b + l * HID, Ahi, Alo);
    k_gnorm<<<NG, 256, 0, stream>>>(Ahi, Alo, gstart, n_alpha + l * HID, n_gamma + l * HID, n_beta + l * HID,
                                    pooled, l == 2 ? 1 : 0);
  }
  k_head<<<NG, 256, 0, stream>>>(pooled, W1t, lin1_b, out_W, out_b, out);
}

// Round 5
// 716.198 us; speedup vs baseline: 1.5713x; 1.0014x over previous
//
#include <hip/hip_runtime.h>
#include <math.h>

#define NN 100000   // nodes
#define NE 300000   // edges
#define NG 2000     // graphs
#define HID 256
#define CIN 59
#define KPAD 64     // CIN padded to MFMA K
#define EPSV 1e-5f

#define SCAN_CHUNK 1024
#define NCHUNK ((NN + SCAN_CHUNK - 1) / SCAN_CHUNK)   // 98

typedef __attribute__((ext_vector_type(8))) short bf16x8;   // 8 bf16 (4 VGPRs)
typedef __attribute__((ext_vector_type(4))) float f32x4;

// Ahi/Alo live in a row-swizzled global layout: element (r,k) is stored at
// ushort index r*HID + (k ^ ((r&7)<<3)).  This makes a LINEAR global->LDS
// copy (global_load_lds) yield a bank-conflict-free ds_read_b128 pattern in
// the GEMM (2-way max = free).  Every producer/consumer of Ahi/Alo must use
// swzk().  XOR key is a multiple of 8 -> any aligned <=8-ushort chunk stays
// contiguous & aligned.
__device__ __forceinline__ int swzk(int row, int k) { return k ^ ((row & 7) << 3); }

// ---------- f32 -> (bf16 hi, bf16 lo) split, round-to-nearest ----------
__device__ inline void splitbf(float x, ushort& hi, ushort& lo) {
  union { float f; unsigned u; } a; a.f = x;
  unsigned r = a.u + 0x7FFFu + ((a.u >> 16) & 1u);
  hi = (ushort)(r >> 16);
  union { unsigned u; float f; } h; h.u = (unsigned)hi << 16;
  union { float f; unsigned u; } d; d.f = x - h.f;
  unsigned r2 = d.u + 0x7FFFu + ((d.u >> 16) & 1u);
  lo = (ushort)(r2 >> 16);
}
__device__ inline float joinbf(ushort hi, ushort lo) {
  union { unsigned u; float f; } a, b;
  a.u = (unsigned)hi << 16; b.u = (unsigned)lo << 16;
  return a.f + b.f;
}

__device__ __forceinline__ void gload16(const ushort* g, ushort* l) {
  __builtin_amdgcn_global_load_lds(
      (const __attribute__((address_space(1))) unsigned int*)g,
      (__attribute__((address_space(3))) unsigned int*)l, 16, 0, 0);
}

// ---------------- degree / CSR build ----------------

__global__ __launch_bounds__(256) void k_deg(const int* __restrict__ ei, int* __restrict__ deg) {
  int e = blockIdx.x * 256 + threadIdx.x;
  if (e < NE) atomicAdd(&deg[ei[NE + e]], 1);   // dst = ei[1][e]
}

__global__ __launch_bounds__(256) void k_dinv(const int* __restrict__ deg, float* __restrict__ dinv) {
  int i = blockIdx.x * 256 + threadIdx.x;
  if (i < NN) dinv[i] = rsqrtf((float)deg[i] + 1.0f);  // +1 self loop
}

__global__ __launch_bounds__(256) void k_scanA(const int* __restrict__ deg, int* __restrict__ part) {
  __shared__ int sm[256];
  int b = blockIdx.x, t = threadIdx.x;
  int base = b * SCAN_CHUNK + t * 4;
  int s = 0;
#pragma unroll
  for (int j = 0; j < 4; ++j) { int idx = base + j; if (idx < NN) s += deg[idx]; }
  sm[t] = s; __syncthreads();
  for (int off = 128; off > 0; off >>= 1) {
    if (t < off) sm[t] += sm[t + off];
    __syncthreads();
  }
  if (t == 0) part[b] = sm[0];
}

__global__ void k_scanB(int* __restrict__ part) {  // 128 threads
  __shared__ int sm[128];
  int t = threadIdx.x;
  int v = (t < NCHUNK) ? part[t] : 0;
  sm[t] = v; __syncthreads();
  for (int off = 1; off < 128; off <<= 1) {
    int x = (t >= off) ? sm[t - off] : 0;
    __syncthreads();
    sm[t] += x;
    __syncthreads();
  }
  if (t < NCHUNK) part[t] = sm[t] - v;  // exclusive
}

__global__ __launch_bounds__(256) void k_scanC(const int* __restrict__ deg, const int* __restrict__ part,
                                               int* __restrict__ row_start, int* __restrict__ pos) {
  __shared__ int sm[256];
  int b = blockIdx.x, t = threadIdx.x;
  int base = b * SCAN_CHUNK + t * 4;
  int v[4]; int s = 0;
#pragma unroll
  for (int j = 0; j < 4; ++j) { int idx = base + j; v[j] = (idx < NN) ? deg[idx] : 0; s += v[j]; }
  sm[t] = s; __syncthreads();
  for (int off = 1; off < 256; off <<= 1) {
    int x = (t >= off) ? sm[t - off] : 0;
    __syncthreads();
    sm[t] += x;
    __syncthreads();
  }
  int excl = sm[t] - s + part[b];
#pragma unroll
  for (int j = 0; j < 4; ++j) {
    int idx = base + j;
    if (idx < NN) { row_start[idx] = excl; pos[idx] = excl; excl += v[j]; }
  }
  if (b == 0 && t == 0) row_start[NN] = NE;
}

__global__ __launch_bounds__(256) void k_csr_fill(const int* __restrict__ ei, int* __restrict__ pos,
                                                  int* __restrict__ csr_src) {
  int e = blockIdx.x * 256 + threadIdx.x;
  if (e >= NE) return;
  int d = ei[NE + e];
  int slot = atomicAdd(&pos[d], 1);
  csr_src[slot] = ei[e];
}

__global__ __launch_bounds__(256) void k_gstart(const int* __restrict__ batch, int* __restrict__ gstart) {
  int i = blockIdx.x * 256 + threadIdx.x;
  if (i >= NN) return;
  int b = batch[i];
  int pb = (i == 0) ? -1 : batch[i - 1];
  for (int g = pb + 1; g <= b; ++g) gstart[g] = i;
  if (i == NN - 1) {
    for (int g = b + 1; g <= NG; ++g) gstart[g] = NN;
  }
}

// ---------------- conv_W -> bf16 hi/lo (unswizzled) ----------------
__global__ __launch_bounds__(256) void k_wcvt(const float* __restrict__ W, ushort* __restrict__ Whi,
                                              ushort* __restrict__ Wlo, int n) {
  int i = blockIdx.x * 256 + threadIdx.x;
  if (i >= n) return;
  ushort h, l; splitbf(W[i], h, l);
  Whi[i] = h; Wlo[i] = l;
}

// ---------------- lin0_W [256][59] -> padded [256][64] hi/lo ----------------
__global__ __launch_bounds__(256) void k_w0cvt(const float* __restrict__ W, ushort* __restrict__ Whi,
                                               ushort* __restrict__ Wlo) {
  int i = blockIdx.x * 256 + threadIdx.x;   // over 256*64
  int row = i >> 6, k = i & 63;
  float v = (k < CIN) ? W[row * CIN + k] : 0.f;
  ushort h, l; splitbf(v, h, l);
  Whi[i] = h; Wlo[i] = l;
}

// ---------------- x [N][59] -> padded [N][64] hi/lo, wave per node ----------------
__global__ __launch_bounds__(256) void k_xcvt(const float* __restrict__ x, ushort* __restrict__ Xhi,
                                              ushort* __restrict__ Xlo) {
  int wid = blockIdx.x * 4 + (threadIdx.x >> 6);
  int lane = threadIdx.x & 63;
  if (wid >= NN) return;
  float v = (lane < CIN) ? x[(size_t)wid * CIN + lane] : 0.f;
  ushort h, l; splitbf(v, h, l);
  Xhi[(size_t)wid * KPAD + lane] = h;
  Xlo[(size_t)wid * KPAD + lane] = l;
}

// ---------------- lin0 via MFMA: H = elu(X @ W0^T + b0) -> swizzled hi/lo ----------------
// 64x256 block tile, 4 waves (64x64 each).  Epilogue stages hi|lo-packed uints
// in LDS (col ^ ((row&7)<<2) -> 2-way max on ds_write_b32), then a linear
// conflict-free copy-out with dense 8B stores into the swizzled global layout.
__global__ __launch_bounds__(256) void k_lin0g(const ushort* __restrict__ Xhi, const ushort* __restrict__ Xlo,
                                               const ushort* __restrict__ Whi, const ushort* __restrict__ Wlo,
                                               const float* __restrict__ bias,
                                               ushort* __restrict__ Ahi, ushort* __restrict__ Alo) {
  __shared__ unsigned sA[64 * HID];   // 64 KB: packed hi | lo<<16
  int tid = threadIdx.x;
  int wave = tid >> 6, lane = tid & 63;
  int m0 = blockIdx.x * 64;
  int n0 = wave * 64;
  int lr = lane & 15;
  int q  = lane >> 4;
  int kg = q * 8;
  f32x4 acc[4][4];
#pragma unroll
  for (int i = 0; i < 4; ++i)
#pragma unroll
    for (int j = 0; j < 4; ++j) { acc[i][j].x = 0.f; acc[i][j].y = 0.f; acc[i][j].z = 0.f; acc[i][j].w = 0.f; }

#pragma unroll
  for (int k0 = 0; k0 < KPAD; k0 += 32) {
    bf16x8 ah[4], al[4], bh[4], bl[4];
#pragma unroll
    for (int i = 0; i < 4; ++i) {
      int row = m0 + i * 16 + lr;
      if (row >= NN) row = NN - 1;
      ah[i] = *(const bf16x8*)(Xhi + (size_t)row * KPAD + k0 + kg);
      al[i] = *(const bf16x8*)(Xlo + (size_t)row * KPAD + k0 + kg);
    }
#pragma unroll
    for (int j = 0; j < 4; ++j) {
      int col = n0 + j * 16 + lr;
      bh[j] = *(const bf16x8*)(Whi + (size_t)col * KPAD + k0 + kg);
      bl[j] = *(const bf16x8*)(Wlo + (size_t)col * KPAD + k0 + kg);
    }
#pragma unroll
    for (int i = 0; i < 4; ++i)
#pragma unroll
      for (int j = 0; j < 4; ++j) {
        acc[i][j] = __builtin_amdgcn_mfma_f32_16x16x32_bf16(ah[i], bh[j], acc[i][j], 0, 0, 0);
        acc[i][j] = __builtin_amdgcn_mfma_f32_16x16x32_bf16(ah[i], bl[j], acc[i][j], 0, 0, 0);
        acc[i][j] = __builtin_amdgcn_mfma_f32_16x16x32_bf16(al[i], bh[j], acc[i][j], 0, 0, 0);
      }
  }
  // ---- epilogue: bias + ELU + split -> packed LDS (local rows 0..63) ----
  // C/D: col = lane&15, row = (lane>>4)*4 + reg
#pragma unroll
  for (int i = 0; i < 4; ++i) {
#pragma unroll
    for (int r = 0; r < 4; ++r) {
      int row = i * 16 + q * 4 + r;             // local row
      int key4 = (row & 7) << 2;
#pragma unroll
      for (int j = 0; j < 4; ++j) {
        int col = n0 + j * 16 + lr;
        float v = acc[i][j][r] + bias[col];
        v = v > 0.f ? v : expm1f(v);            // ELU
        ushort h, l; splitbf(v, h, l);
        sA[row * HID + (col ^ key4)] = (unsigned)h | ((unsigned)l << 16);
      }
    }
  }
  __syncthreads();
  // ---- copy-out: 16 rounds, thread = one 4-col chunk of one row ----
#pragma unroll
  for (int rd = 0; rd < 16; ++rd) {
    int row = (tid >> 6) + rd * 4;              // 0..63
    int col0 = (tid & 63) * 4;                  // 4-aligned
    int key4 = (row & 7) << 2, key8 = (row & 7) << 3;
    int grow = m0 + row;
    uint4 u = *(const uint4*)&sA[row * HID + (col0 ^ key4)];
    if (grow < NN) {
      uint2 hv, lv;
      hv.x = (u.x & 0xffffu) | (u.y << 16);
      hv.y = (u.z & 0xffffu) | (u.w << 16);
      lv.x = (u.x >> 16) | (u.y & 0xffff0000u);
      lv.y = (u.z >> 16) | (u.w & 0xffff0000u);
      *(uint2*)(Ahi + (size_t)grow * HID + (col0 ^ key8)) = hv;
      *(uint2*)(Alo + (size_t)grow * HID + (col0 ^ key8)) = lv;
    }
  }
}

// ---------------- MFMA split-bf16 GEMM: C = A @ W^T ----------------
// BM=64, 4 waves; full-K A-tile (hi+lo, 64 KB) LDS-resident via global_load_lds.
// 2 blocks/CU (LDS-capped) -> one block computes while the other streams HBM.
#define GBM 64
__global__ __launch_bounds__(256) void k_gemm_mfma(const ushort* __restrict__ Ahi, const ushort* __restrict__ Alo,
                                                   const ushort* __restrict__ Whi, const ushort* __restrict__ Wlo,
                                                   float* __restrict__ C, int M) {
  __shared__ ushort sAhi[GBM * HID];   // 32 KB, linear copy of swizzled global
  __shared__ ushort sAlo[GBM * HID];   // 32 KB
  int tid = threadIdx.x;
  int wave = tid >> 6, lane = tid & 63;
  int m0 = blockIdx.x * GBM;
  int n0 = wave * 64;
  int lr = lane & 15;
  int q  = lane >> 4;
  int kg = q * 8;

  // ---- stage A tile: 32 segments x 1024 B per buffer, 8 per wave ----
  const ushort* gh = Ahi + (size_t)m0 * HID;
  const ushort* gl = Alo + (size_t)m0 * HID;
#pragma unroll
  for (int sgm = 0; sgm < 8; ++sgm) {
    int seg = sgm * 4 + wave;            // 0..31
    gload16(gh + seg * 512 + lane * 8, &sAhi[seg * 512]);
    gload16(gl + seg * 512 + lane * 8, &sAlo[seg * 512]);
  }
  __syncthreads();   // drains vmcnt -> LDS tile complete

  f32x4 acc[4][4];
#pragma unroll
  for (int i = 0; i < 4; ++i)
#pragma unroll
    for (int j = 0; j < 4; ++j) { acc[i][j].x = 0.f; acc[i][j].y = 0.f; acc[i][j].z = 0.f; acc[i][j].w = 0.f; }

#pragma unroll 2
  for (int k0 = 0; k0 < HID; k0 += 32) {
    bf16x8 ah[4], al[4], bh[4], bl[4];
#pragma unroll
    for (int j = 0; j < 4; ++j) {        // W from L2 (hot: 131 KB x2 per layer)
      int col = n0 + j * 16 + lr;
      bh[j] = *(const bf16x8*)(Whi + (size_t)col * HID + k0 + kg);
      bl[j] = *(const bf16x8*)(Wlo + (size_t)col * HID + k0 + kg);
    }
#pragma unroll
    for (int i = 0; i < 4; ++i) {        // A from LDS, swizzled -> 2-way max
      int row = i * 16 + lr;
      int kk = swzk(row, k0 + kg);
      ah[i] = *(const bf16x8*)&sAhi[row * HID + kk];
      al[i] = *(const bf16x8*)&sAlo[row * HID + kk];
    }
#pragma unroll
    for (int i = 0; i < 4; ++i)
#pragma unroll
      for (int j = 0; j < 4; ++j) {
        acc[i][j] = __builtin_amdgcn_mfma_f32_16x16x32_bf16(ah[i], bh[j], acc[i][j], 0, 0, 0);
        acc[i][j] = __builtin_amdgcn_mfma_f32_16x16x32_bf16(ah[i], bl[j], acc[i][j], 0, 0, 0);
        acc[i][j] = __builtin_amdgcn_mfma_f32_16x16x32_bf16(al[i], bh[j], acc[i][j], 0, 0, 0);
      }
  }
  // C/D: col = lane&15, row = (lane>>4)*4 + reg
#pragma unroll
  for (int i = 0; i < 4; ++i) {
#pragma unroll
    for (int r = 0; r < 4; ++r) {
      int row = m0 + i * 16 + q * 4 + r;
      if (row < M) {
        float* cp = C + (size_t)row * HID + n0 + lr;
        cp[0]  = acc[i][0][r];
        cp[16] = acc[i][1][r];
        cp[32] = acc[i][2][r];
        cp[48] = acc[i][3][r];
      }
    }
  }
}

// ---------------- aggregate: one wave per dst node -> swizzled bf16 hi/lo ----------------
__global__ __launch_bounds__(256) void k_aggregate(const float* __restrict__ T, const float* __restrict__ dinv,
                                                   const int* __restrict__ row_start, const int* __restrict__ csr_src,
                                                   const float* __restrict__ bias,
                                                   ushort* __restrict__ Ahi, ushort* __restrict__ Alo) {
  int wid = blockIdx.x * 4 + (threadIdx.x >> 6);
  int lane = threadIdx.x & 63;
  if (wid >= NN) return;
  float di = dinv[wid];
  int s = row_start[wid], e = row_start[wid + 1];
  float4 acc = make_float4(0.f, 0.f, 0.f, 0.f);
  for (int t = s; t < e; ++t) {
    int src = csr_src[t];
    float c = dinv[src] * di;
    float4 v = ((const float4*)(T + (size_t)src * HID))[lane];
    acc.x = fmaf(v.x, c, acc.x); acc.y = fmaf(v.y, c, acc.y);
    acc.z = fmaf(v.z, c, acc.z); acc.w = fmaf(v.w, c, acc.w);
  }
  float4 v = ((const float4*)(T + (size_t)wid * HID))[lane];
  float sc = di * di;
  float4 bb = ((const float4*)bias)[lane];
  acc.x = fmaf(v.x, sc, acc.x) + bb.x;
  acc.y = fmaf(v.y, sc, acc.y) + bb.y;
  acc.z = fmaf(v.z, sc, acc.z) + bb.z;
  acc.w = fmaf(v.w, sc, acc.w) + bb.w;
  ushort4 h4, l4;
  splitbf(acc.x, h4.x, l4.x); splitbf(acc.y, h4.y, l4.y);
  splitbf(acc.z, h4.z, l4.z); splitbf(acc.w, h4.w, l4.w);
  int kc = swzk(wid, lane * 4);
  *(ushort4*)(Ahi + (size_t)wid * HID + kc) = h4;
  *(ushort4*)(Alo + (size_t)wid * HID + kc) = l4;
}

// ---------------- GraphNorm (+ReLU, + pool on last layer), in-place on swizzled hi/lo ----------------
__global__ __launch_bounds__(256) void k_gnorm(ushort* __restrict__ Ahi, ushort* __restrict__ Alo,
                                               const int* __restrict__ gstart,
                                               const float* __restrict__ alpha, const float* __restrict__ gamma,
                                               const float* __restrict__ beta, float* __restrict__ pooled,
                                               int last) {
  __shared__ float4 smA[4][64];
  __shared__ float4 smB[4][64];
  int g = blockIdx.x;
  int r = threadIdx.x >> 6;        // 0..3
  int cg = threadIdx.x & 63;       // channel group
  int c0 = cg * 4;
  int s = gstart[g], e = gstart[g + 1];
  int n = e - s;
  float cnt = (float)(n > 1 ? n : 1);
  float s1[4] = {0.f, 0.f, 0.f, 0.f}, s2[4] = {0.f, 0.f, 0.f, 0.f};
  for (int i = s + r; i < e; i += 4) {
    int kc = swzk(i, c0);
    ushort4 h = *(const ushort4*)(Ahi + (size_t)i * HID + kc);
    ushort4 l = *(const ushort4*)(Alo + (size_t)i * HID + kc);
    float v0 = joinbf(h.x, l.x), v1 = joinbf(h.y, l.y), v2 = joinbf(h.z, l.z), v3 = joinbf(h.w, l.w);
    s1[0] += v0; s2[0] = fmaf(v0, v0, s2[0]);
    s1[1] += v1; s2[1] = fmaf(v1, v1, s2[1]);
    s1[2] += v2; s2[2] = fmaf(v2, v2, s2[2]);
    s1[3] += v3; s2[3] = fmaf(v3, v3, s2[3]);
  }
  smA[r][cg] = make_float4(s1[0], s1[1], s1[2], s1[3]);
  smB[r][cg] = make_float4(s2[0], s2[1], s2[2], s2[3]);
  __syncthreads();
  float4 a0 = smA[0][cg], a1 = smA[1][cg], a2 = smA[2][cg], a3 = smA[3][cg];
  float4 b0 = smB[0][cg], b1 = smB[1][cg], b2 = smB[2][cg], b3 = smB[3][cg];
  float t1[4] = {a0.x + a1.x + a2.x + a3.x, a0.y + a1.y + a2.y + a3.y,
                 a0.z + a1.z + a2.z + a3.z, a0.w + a1.w + a2.w + a3.w};
  float t2[4] = {b0.x + b1.x + b2.x + b3.x, b0.y + b1.y + b2.y + b3.y,
                 b0.z + b1.z + b2.z + b3.z, b0.w + b1.w + b2.w + b3.w};
  float4 al4 = *(const float4*)(alpha + c0);
  float4 ga4 = *(const float4*)(gamma + c0);
  float4 be4 = *(const float4*)(beta + c0);
  float am[4], rs[4], be[4];
  float alv[4] = {al4.x, al4.y, al4.z, al4.w};
  float gav[4] = {ga4.x, ga4.y, ga4.z, ga4.w};
  float bev[4] = {be4.x, be4.y, be4.z, be4.w};
#pragma unroll
  for (int j = 0; j < 4; ++j) {
    float mean = t1[j] / cnt;
    float a = alv[j] * mean;
    float var = t2[j] / cnt - 2.f * a * mean + a * a;
    am[j] = a;
    rs[j] = rsqrtf(var + EPSV) * gav[j];
    be[j] = bev[j];
  }
  if (last) {
    float p[4] = {0.f, 0.f, 0.f, 0.f};
    for (int i = s + r; i < e; i += 4) {
      int kc = swzk(i, c0);
      ushort4 h = *(const ushort4*)(Ahi + (size_t)i * HID + kc);
      ushort4 l = *(const ushort4*)(Alo + (size_t)i * HID + kc);
      float v[4] = {joinbf(h.x, l.x), joinbf(h.y, l.y), joinbf(h.z, l.z), joinbf(h.w, l.w)};
#pragma unroll
      for (int j = 0; j < 4; ++j) p[j] += fmaxf((v[j] - am[j]) * rs[j] + be[j], 0.f);
    }
    __syncthreads();   // WAR on smA
    smA[r][cg] = make_float4(p[0], p[1], p[2], p[3]);
    __syncthreads();
    if (r == 0) {
      float4 p0 = smA[0][cg], p1 = smA[1][cg], p2 = smA[2][cg], p3 = smA[3][cg];
      float4 o = make_float4(p0.x + p1.x + p2.x + p3.x, p0.y + p1.y + p2.y + p3.y,
                             p0.z + p1.z + p2.z + p3.z, p0.w + p1.w + p2.w + p3.w);
      *(float4*)(pooled + g * HID + c0) = o;
    }
  } else {
    for (int i = s + r; i < e; i += 4) {
      int kc = swzk(i, c0);
      ushort4 h = *(const ushort4*)(Ahi + (size_t)i * HID + kc);
      ushort4 l = *(const ushort4*)(Alo + (size_t)i * HID + kc);
      float v[4] = {joinbf(h.x, l.x), joinbf(h.y, l.y), joinbf(h.z, l.z), joinbf(h.w, l.w)};
      ushort4 ho, lo4;
      float o0 = fmaxf((v[0] - am[0]) * rs[0] + be[0], 0.f);
      float o1 = fmaxf((v[1] - am[1]) * rs[1] + be[1], 0.f);
      float o2 = fmaxf((v[2] - am[2]) * rs[2] + be[2], 0.f);
      float o3 = fmaxf((v[3] - am[3]) * rs[3] + be[3], 0.f);
      splitbf(o0, ho.x, lo4.x); splitbf(o1, ho.y, lo4.y);
      splitbf(o2, ho.z, lo4.z); splitbf(o3, ho.w, lo4.w);
      *(ushort4*)(Ahi + (size_t)i * HID + kc) = ho;
      *(ushort4*)(Alo + (size_t)i * HID + kc) = lo4;
    }
  }
}

// ---------------- W1 transpose ----------------
__global__ void k_transpose(const float* __restrict__ W, float* __restrict__ Wt) {
  __shared__ float tile[32][33];
  int bx = blockIdx.x, by = blockIdx.y;
  int tx = threadIdx.x, ty = threadIdx.y;   // 32 x 8
  for (int r = 0; r < 32; r += 8)
    tile[ty + r][tx] = W[(size_t)(by * 32 + ty + r) * HID + bx * 32 + tx];
  __syncthreads();
  for (int r = 0; r < 32; r += 8)
    Wt[(size_t)(bx * 32 + ty + r) * HID + by * 32 + tx] = tile[tx][ty + r];
}

// ---------------- head ----------------
__global__ __launch_bounds__(256) void k_head(const float* __restrict__ pooled, const float* __restrict__ W1t,
                                              const float* __restrict__ b1, const float* __restrict__ Wout,
                                              const float* __restrict__ bout, float* __restrict__ out) {
  int g = blockIdx.x, t = threadIdx.x;
  __shared__ float gv[HID];
  __shared__ float red[HID];
  gv[t] = pooled[g * HID + t];
  __syncthreads();
  float acc = b1[t];
  for (int k = 0; k < HID; ++k) acc = fmaf(gv[k], W1t[k * HID + t], acc);
  float h = fmaxf(acc, 0.f);
  red[t] = h * Wout[t];
  __syncthreads();
  for (int off = 128; off > 0; off >>= 1) {
    if (t < off) red[t] += red[t + off];
    __syncthreads();
  }
  if (t == 0) out[g] = 1.f / (1.f + expf(-(red[0] + bout[0])));
}

// ---------------- launch ----------------
extern "C" void kernel_launch(void* const* d_in, const int* in_sizes, int n_in,
                              void* d_out, int out_size, void* d_ws, size_t ws_size,
                              hipStream_t stream) {
  const float* x          = (const float*)d_in[0];
  const int*   edge_index = (const int*)d_in[1];
  const int*   batch      = (const int*)d_in[2];
  const float* lin0_W     = (const float*)d_in[3];
  const float* lin0_b     = (const float*)d_in[4];
  const float* conv_W     = (const float*)d_in[5];
  const float* conv_b     = (const float*)d_in[6];
  const float* n_alpha    = (const float*)d_in[7];
  const float* n_gamma    = (const float*)d_in[8];
  const float* n_beta     = (const float*)d_in[9];
  const float* lin1_W     = (const float*)d_in[10];
  const float* lin1_b     = (const float*)d_in[11];
  const float* out_W      = (const float*)d_in[12];
  const float* out_b      = (const float*)d_in[13];
  float* out = (float*)d_out;

  char* ws = (char*)d_ws;
  size_t off = 0;
  auto nxt = [&](size_t bytes) { size_t o = off; off += (bytes + 255) & ~(size_t)255; return o; };
  ushort* Ahi    = (ushort*)(ws + nxt((size_t)NN * HID * 2));
  ushort* Alo    = (ushort*)(ws + nxt((size_t)NN * HID * 2));
  char*   tbase  = ws + nxt((size_t)NN * HID * 4);        // Tbuf block, sub-carved:
  float*  Tbuf   = (float*)tbase;                          //   GEMM output (layers)
  ushort* Xhi    = (ushort*)tbase;                          //   [0, 12.8MB) dead after lin0g
  ushort* Xlo    = (ushort*)(tbase + (size_t)NN * KPAD * 2);//   [12.8, 25.6MB) dead after lin0g
  float*  dinv   = (float*) (ws + nxt((size_t)NN * 4));
  int*    deg    = (int*)   (ws + nxt((size_t)NN * 4));
  int*    rstart = (int*)   (ws + nxt((size_t)(NN + 1) * 4));
  int*    csrsrc = (int*)   (ws + nxt((size_t)NE * 4));
  int*    gstart = (int*)   (ws + nxt((size_t)(NG + 1) * 4));
  char*   poolbase = ws + nxt((size_t)NG * HID * 4);       // 2,048,000 B block, sub-carved:
  float*  pooled = (float*)poolbase;                        //   written only at layer-3 gnorm
  int*    pos    = (int*)(poolbase);                        //   [0, 400000) dead after csr_fill
  ushort* Whi    = (ushort*)(poolbase + 400384);            //   dead after last gemm
  ushort* Wlo    = (ushort*)(poolbase + 793600);            //   dead after last gemm
  float*  W1t    = (float*) (ws + nxt((size_t)HID * HID * 4));
  ushort* W0hi   = (ushort*)(ws + nxt((size_t)HID * KPAD * 2));
  ushort* W0lo   = (ushort*)(ws + nxt((size_t)HID * KPAD * 2));
  int*    part   = (int*)   (ws + nxt((size_t)NCHUNK * 4));
  (void)ws_size; (void)in_sizes; (void)n_in; (void)out_size;

  hipMemsetAsync(deg, 0, (size_t)NN * 4, stream);
  k_deg<<<(NE + 255) / 256, 256, 0, stream>>>(edge_index, deg);
  k_dinv<<<(NN + 255) / 256, 256, 0, stream>>>(deg, dinv);
  k_scanA<<<NCHUNK, 256, 0, stream>>>(deg, part);
  k_scanB<<<1, 128, 0, stream>>>(part);
  k_scanC<<<NCHUNK, 256, 0, stream>>>(deg, part, rstart, pos);
  k_csr_fill<<<(NE + 255) / 256, 256, 0, stream>>>(edge_index, pos, csrsrc);
  k_gstart<<<(NN + 255) / 256, 256, 0, stream>>>(batch, gstart);
  k_wcvt<<<(3 * HID * HID + 255) / 256, 256, 0, stream>>>(conv_W, Whi, Wlo, 3 * HID * HID);
  k_w0cvt<<<(HID * KPAD) / 256, 256, 0, stream>>>(lin0_W, W0hi, W0lo);
  k_xcvt<<<(NN + 3) / 4, 256, 0, stream>>>(x, Xhi, Xlo);
  k_lin0g<<<(NN + 63) / 64, 256, 0, stream>>>(Xhi, Xlo, W0hi, W0lo, lin0_b, Ahi, Alo);
  k_transpose<<<dim3(8, 8), dim3(32, 8), 0, stream>>>(lin1_W, W1t);

  for (int l = 0; l < 3; ++l) {
    k_gemm_mfma<<<(NN + GBM - 1) / GBM, 256, 0, stream>>>(
        Ahi, Alo, Whi + (size_t)l * HID * HID, Wlo + (size_t)l * HID * HID, Tbuf, NN);
    k_aggregate<<<(NN + 3) / 4, 256, 0, stream>>>(Tbuf, dinv, rstart, csrsrc, conv_b + l * HID, Ahi, Alo);
    k_gnorm<<<NG, 256, 0, stream>>>(Ahi, Alo, gstart, n_alpha + l * HID, n_gamma + l * HID, n_beta + l * HID,
                                    pooled, l == 2 ? 1 : 0);
  }
  k_head<<<NG, 256, 0, stream>>>(pooled, W1t, lin1_b, out_W, out_b, out);
}

// Round 6
// 690.757 us; speedup vs baseline: 1.6292x; 1.0368x over previous
//
#include <hip/hip_runtime.h>
#include <math.h>

#define NN 100000   // nodes
#define NE 300000   // edges
#define NG 2000     // graphs
#define HID 256
#define CIN 59
#define KPAD 64     // CIN padded to MFMA K
#define EPSV 1e-5f

#define SCAN_CHUNK 1024
#define NCHUNK ((NN + SCAN_CHUNK - 1) / SCAN_CHUNK)   // 98

typedef __attribute__((ext_vector_type(8))) short bf16x8;   // 8 bf16 (4 VGPRs)
typedef __attribute__((ext_vector_type(4))) float f32x4;

union Frag { unsigned u[4]; bf16x8 v; };

// Ahi/Alo (layer activations) live in a row-swizzled global layout: element
// (r,k) at ushort index r*HID + (k ^ ((r&7)<<3)).  Linear global->LDS copy
// then yields conflict-free ds_read_b128 in the GEMM.  All producers and
// consumers of Ahi/Alo use swzk().
__device__ __forceinline__ int swzk(int row, int k) { return k ^ ((row & 7) << 3); }

// ---------- f32 -> (bf16 hi, bf16 lo) split, round-to-nearest ----------
__device__ inline void splitbf(float x, ushort& hi, ushort& lo) {
  union { float f; unsigned u; } a; a.f = x;
  unsigned r = a.u + 0x7FFFu + ((a.u >> 16) & 1u);
  hi = (ushort)(r >> 16);
  union { unsigned u; float f; } h; h.u = (unsigned)hi << 16;
  union { float f; unsigned u; } d; d.f = x - h.f;
  unsigned r2 = d.u + 0x7FFFu + ((d.u >> 16) & 1u);
  lo = (ushort)(r2 >> 16);
}
__device__ inline float joinbf(ushort hi, ushort lo) {
  union { unsigned u; float f; } a, b;
  a.u = (unsigned)hi << 16; b.u = (unsigned)lo << 16;
  return a.f + b.f;
}

__device__ __forceinline__ void gload16(const ushort* g, ushort* l) {
  __builtin_amdgcn_global_load_lds(
      (const __attribute__((address_space(1))) unsigned int*)g,
      (__attribute__((address_space(3))) unsigned int*)l, 16, 0, 0);
}

// ---------------- degree / CSR build ----------------

__global__ __launch_bounds__(256) void k_deg(const int* __restrict__ ei, int* __restrict__ deg) {
  int e = blockIdx.x * 256 + threadIdx.x;
  if (e < NE) atomicAdd(&deg[ei[NE + e]], 1);   // dst = ei[1][e]
}

__global__ __launch_bounds__(256) void k_dinv(const int* __restrict__ deg, float* __restrict__ dinv) {
  int i = blockIdx.x * 256 + threadIdx.x;
  if (i < NN) dinv[i] = rsqrtf((float)deg[i] + 1.0f);  // +1 self loop
}

__global__ __launch_bounds__(256) void k_scanA(const int* __restrict__ deg, int* __restrict__ part) {
  __shared__ int sm[256];
  int b = blockIdx.x, t = threadIdx.x;
  int base = b * SCAN_CHUNK + t * 4;
  int s = 0;
#pragma unroll
  for (int j = 0; j < 4; ++j) { int idx = base + j; if (idx < NN) s += deg[idx]; }
  sm[t] = s; __syncthreads();
  for (int off = 128; off > 0; off >>= 1) {
    if (t < off) sm[t] += sm[t + off];
    __syncthreads();
  }
  if (t == 0) part[b] = sm[0];
}

__global__ void k_scanB(int* __restrict__ part) {  // 128 threads
  __shared__ int sm[128];
  int t = threadIdx.x;
  int v = (t < NCHUNK) ? part[t] : 0;
  sm[t] = v; __syncthreads();
  for (int off = 1; off < 128; off <<= 1) {
    int x = (t >= off) ? sm[t - off] : 0;
    __syncthreads();
    sm[t] += x;
    __syncthreads();
  }
  if (t < NCHUNK) part[t] = sm[t] - v;  // exclusive
}

__global__ __launch_bounds__(256) void k_scanC(const int* __restrict__ deg, const int* __restrict__ part,
                                               int* __restrict__ row_start, int* __restrict__ pos) {
  __shared__ int sm[256];
  int b = blockIdx.x, t = threadIdx.x;
  int base = b * SCAN_CHUNK + t * 4;
  int v[4]; int s = 0;
#pragma unroll
  for (int j = 0; j < 4; ++j) { int idx = base + j; v[j] = (idx < NN) ? deg[idx] : 0; s += v[j]; }
  sm[t] = s; __syncthreads();
  for (int off = 1; off < 256; off <<= 1) {
    int x = (t >= off) ? sm[t - off] : 0;
    __syncthreads();
    sm[t] += x;
    __syncthreads();
  }
  int excl = sm[t] - s + part[b];
#pragma unroll
  for (int j = 0; j < 4; ++j) {
    int idx = base + j;
    if (idx < NN) { row_start[idx] = excl; pos[idx] = excl; excl += v[j]; }
  }
  if (b == 0 && t == 0) row_start[NN] = NE;
}

__global__ __launch_bounds__(256) void k_csr_fill(const int* __restrict__ ei, int* __restrict__ pos,
                                                  int* __restrict__ csr_src) {
  int e = blockIdx.x * 256 + threadIdx.x;
  if (e >= NE) return;
  int d = ei[NE + e];
  int slot = atomicAdd(&pos[d], 1);
  csr_src[slot] = ei[e];
}

__global__ __launch_bounds__(256) void k_gstart(const int* __restrict__ batch, int* __restrict__ gstart) {
  int i = blockIdx.x * 256 + threadIdx.x;
  if (i >= NN) return;
  int b = batch[i];
  int pb = (i == 0) ? -1 : batch[i - 1];
  for (int g = pb + 1; g <= b; ++g) gstart[g] = i;
  if (i == NN - 1) {
    for (int g = b + 1; g <= NG; ++g) gstart[g] = NN;
  }
}

// ---------------- conv_W -> bf16 hi/lo (unswizzled) ----------------
__global__ __launch_bounds__(256) void k_wcvt(const float* __restrict__ W, ushort* __restrict__ Whi,
                                              ushort* __restrict__ Wlo, int n) {
  int i = blockIdx.x * 256 + threadIdx.x;
  if (i >= n) return;
  ushort h, l; splitbf(W[i], h, l);
  Whi[i] = h; Wlo[i] = l;
}

// ---------------- lin0_W [256][59] -> padded [256][64] hi/lo ----------------
__global__ __launch_bounds__(256) void k_w0cvt(const float* __restrict__ W, ushort* __restrict__ Whi,
                                               ushort* __restrict__ Wlo) {
  int i = blockIdx.x * 256 + threadIdx.x;   // over 256*64
  int row = i >> 6, k = i & 63;
  float v = (k < CIN) ? W[row * CIN + k] : 0.f;
  ushort h, l; splitbf(v, h, l);
  Whi[i] = h; Wlo[i] = l;
}

// ---------------- x [N][59] -> padded [N][64] hi/lo, wave per node ----------------
__global__ __launch_bounds__(256) void k_xcvt(const float* __restrict__ x, ushort* __restrict__ Xhi,
                                              ushort* __restrict__ Xlo) {
  int wid = blockIdx.x * 4 + (threadIdx.x >> 6);
  int lane = threadIdx.x & 63;
  if (wid >= NN) return;
  float v = (lane < CIN) ? x[(size_t)wid * CIN + lane] : 0.f;
  ushort h, l; splitbf(v, h, l);
  Xhi[(size_t)wid * KPAD + lane] = h;
  Xlo[(size_t)wid * KPAD + lane] = l;
}

// ---------------- FUSED lin0 + conv0: T = (elu(X@W0^T+b0)) @ Wc^T ----------------
// Per 64-row block: phase1 MFMA lin0 (K=64) -> pack hi|lo<<16 uints into LDS
// (col ^ ((row&7)<<2): writes 2-way, b128 reads balanced = conflict-free) ->
// phase2 MFMA GEMM over K=256 from LDS.  A never touches global memory.
__global__ __launch_bounds__(256) void k_l0conv(const ushort* __restrict__ Xhi, const ushort* __restrict__ Xlo,
                                                const ushort* __restrict__ W0hi, const ushort* __restrict__ W0lo,
                                                const float* __restrict__ bias0,
                                                const ushort* __restrict__ Wchi, const ushort* __restrict__ Wclo,
                                                float* __restrict__ T) {
  __shared__ unsigned sA[64 * HID];   // 64 KB packed
  int tid = threadIdx.x;
  int wave = tid >> 6, lane = tid & 63;
  int m0 = blockIdx.x * 64;
  int n0 = wave * 64;
  int lr = lane & 15;
  int q  = lane >> 4;
  int kg = q * 8;
  f32x4 acc[4][4];
#pragma unroll
  for (int i = 0; i < 4; ++i)
#pragma unroll
    for (int j = 0; j < 4; ++j) { acc[i][j].x = 0.f; acc[i][j].y = 0.f; acc[i][j].z = 0.f; acc[i][j].w = 0.f; }

  // ---- phase 1: A = elu(X @ W0^T + b0) ----
#pragma unroll
  for (int k0 = 0; k0 < KPAD; k0 += 32) {
    bf16x8 ah[4], al[4], bh[4], bl[4];
#pragma unroll
    for (int i = 0; i < 4; ++i) {
      int row = m0 + i * 16 + lr;
      if (row >= NN) row = NN - 1;
      ah[i] = *(const bf16x8*)(Xhi + (size_t)row * KPAD + k0 + kg);
      al[i] = *(const bf16x8*)(Xlo + (size_t)row * KPAD + k0 + kg);
    }
#pragma unroll
    for (int j = 0; j < 4; ++j) {
      int col = n0 + j * 16 + lr;
      bh[j] = *(const bf16x8*)(W0hi + (size_t)col * KPAD + k0 + kg);
      bl[j] = *(const bf16x8*)(W0lo + (size_t)col * KPAD + k0 + kg);
    }
#pragma unroll
    for (int i = 0; i < 4; ++i)
#pragma unroll
      for (int j = 0; j < 4; ++j) {
        acc[i][j] = __builtin_amdgcn_mfma_f32_16x16x32_bf16(ah[i], bh[j], acc[i][j], 0, 0, 0);
        acc[i][j] = __builtin_amdgcn_mfma_f32_16x16x32_bf16(ah[i], bl[j], acc[i][j], 0, 0, 0);
        acc[i][j] = __builtin_amdgcn_mfma_f32_16x16x32_bf16(al[i], bh[j], acc[i][j], 0, 0, 0);
      }
  }
  // ---- epilogue: bias + ELU + split -> packed LDS ----
  float bb[4];
#pragma unroll
  for (int j = 0; j < 4; ++j) bb[j] = bias0[n0 + j * 16 + lr];
  // C/D: col = lane&15, row = (lane>>4)*4 + reg
#pragma unroll
  for (int i = 0; i < 4; ++i) {
#pragma unroll
    for (int r = 0; r < 4; ++r) {
      int row = i * 16 + q * 4 + r;             // local row
      int key = (row & 7) << 2;                 // uint-index XOR key
#pragma unroll
      for (int j = 0; j < 4; ++j) {
        int col = n0 + j * 16 + lr;
        float v = acc[i][j][r] + bb[j];
        v = v > 0.f ? v : expm1f(v);            // ELU
        ushort h, l; splitbf(v, h, l);
        sA[row * HID + (col ^ key)] = (unsigned)h | ((unsigned)l << 16);
      }
    }
  }
  __syncthreads();

  // ---- phase 2: T = A @ Wc^T, A-fragments from LDS ----
#pragma unroll
  for (int i = 0; i < 4; ++i)
#pragma unroll
    for (int j = 0; j < 4; ++j) { acc[i][j].x = 0.f; acc[i][j].y = 0.f; acc[i][j].z = 0.f; acc[i][j].w = 0.f; }

#pragma unroll 2
  for (int k0 = 0; k0 < HID; k0 += 32) {
    bf16x8 ah[4], al[4], bh[4], bl[4];
#pragma unroll
    for (int j = 0; j < 4; ++j) {       // W from L2
      int col = n0 + j * 16 + lr;
      bh[j] = *(const bf16x8*)(Wchi + (size_t)col * HID + k0 + kg);
      bl[j] = *(const bf16x8*)(Wclo + (size_t)col * HID + k0 + kg);
    }
#pragma unroll
    for (int i = 0; i < 4; ++i) {       // A from LDS (packed), unpack hi/lo
      int row = i * 16 + lr;
      int key = (row & 7) << 2;
      int c0 = k0 + kg;
      uint4 u0 = *(const uint4*)&sA[row * HID + (c0 ^ key)];
      uint4 u1 = *(const uint4*)&sA[row * HID + ((c0 + 4) ^ key)];
      Frag fh, fl;
      fh.u[0] = (u0.x & 0xffffu) | (u0.y << 16);
      fh.u[1] = (u0.z & 0xffffu) | (u0.w << 16);
      fh.u[2] = (u1.x & 0xffffu) | (u1.y << 16);
      fh.u[3] = (u1.z & 0xffffu) | (u1.w << 16);
      fl.u[0] = (u0.x >> 16) | (u0.y & 0xffff0000u);
      fl.u[1] = (u0.z >> 16) | (u0.w & 0xffff0000u);
      fl.u[2] = (u1.x >> 16) | (u1.y & 0xffff0000u);
      fl.u[3] = (u1.z >> 16) | (u1.w & 0xffff0000u);
      ah[i] = fh.v; al[i] = fl.v;
    }
#pragma unroll
    for (int i = 0; i < 4; ++i)
#pragma unroll
      for (int j = 0; j < 4; ++j) {
        acc[i][j] = __builtin_amdgcn_mfma_f32_16x16x32_bf16(ah[i], bh[j], acc[i][j], 0, 0, 0);
        acc[i][j] = __builtin_amdgcn_mfma_f32_16x16x32_bf16(ah[i], bl[j], acc[i][j], 0, 0, 0);
        acc[i][j] = __builtin_amdgcn_mfma_f32_16x16x32_bf16(al[i], bh[j], acc[i][j], 0, 0, 0);
      }
  }
  // write T  (C/D: col = lane&15, row = (lane>>4)*4 + reg)
#pragma unroll
  for (int i = 0; i < 4; ++i) {
#pragma unroll
    for (int r = 0; r < 4; ++r) {
      int row = m0 + i * 16 + q * 4 + r;
      if (row < NN) {
        float* cp = T + (size_t)row * HID + n0 + lr;
        cp[0]  = acc[i][0][r];
        cp[16] = acc[i][1][r];
        cp[32] = acc[i][2][r];
        cp[48] = acc[i][3][r];
      }
    }
  }
}

// ---------------- MFMA split-bf16 GEMM: C = A @ W^T (layers 1,2) ----------------
#define GBM 64
__global__ __launch_bounds__(256) void k_gemm_mfma(const ushort* __restrict__ Ahi, const ushort* __restrict__ Alo,
                                                   const ushort* __restrict__ Whi, const ushort* __restrict__ Wlo,
                                                   float* __restrict__ C, int M) {
  __shared__ ushort sAhi[GBM * HID];   // 32 KB, linear copy of swizzled global
  __shared__ ushort sAlo[GBM * HID];   // 32 KB
  int tid = threadIdx.x;
  int wave = tid >> 6, lane = tid & 63;
  int m0 = blockIdx.x * GBM;
  int n0 = wave * 64;
  int lr = lane & 15;
  int q  = lane >> 4;
  int kg = q * 8;

  const ushort* gh = Ahi + (size_t)m0 * HID;
  const ushort* gl = Alo + (size_t)m0 * HID;
#pragma unroll
  for (int sgm = 0; sgm < 8; ++sgm) {
    int seg = sgm * 4 + wave;            // 0..31
    gload16(gh + seg * 512 + lane * 8, &sAhi[seg * 512]);
    gload16(gl + seg * 512 + lane * 8, &sAlo[seg * 512]);
  }
  __syncthreads();

  f32x4 acc[4][4];
#pragma unroll
  for (int i = 0; i < 4; ++i)
#pragma unroll
    for (int j = 0; j < 4; ++j) { acc[i][j].x = 0.f; acc[i][j].y = 0.f; acc[i][j].z = 0.f; acc[i][j].w = 0.f; }

#pragma unroll 2
  for (int k0 = 0; k0 < HID; k0 += 32) {
    bf16x8 ah[4], al[4], bh[4], bl[4];
#pragma unroll
    for (int j = 0; j < 4; ++j) {
      int col = n0 + j * 16 + lr;
      bh[j] = *(const bf16x8*)(Whi + (size_t)col * HID + k0 + kg);
      bl[j] = *(const bf16x8*)(Wlo + (size_t)col * HID + k0 + kg);
    }
#pragma unroll
    for (int i = 0; i < 4; ++i) {
      int row = i * 16 + lr;
      int kk = swzk(row, k0 + kg);
      ah[i] = *(const bf16x8*)&sAhi[row * HID + kk];
      al[i] = *(const bf16x8*)&sAlo[row * HID + kk];
    }
#pragma unroll
    for (int i = 0; i < 4; ++i)
#pragma unroll
      for (int j = 0; j < 4; ++j) {
        acc[i][j] = __builtin_amdgcn_mfma_f32_16x16x32_bf16(ah[i], bh[j], acc[i][j], 0, 0, 0);
        acc[i][j] = __builtin_amdgcn_mfma_f32_16x16x32_bf16(ah[i], bl[j], acc[i][j], 0, 0, 0);
        acc[i][j] = __builtin_amdgcn_mfma_f32_16x16x32_bf16(al[i], bh[j], acc[i][j], 0, 0, 0);
      }
  }
#pragma unroll
  for (int i = 0; i < 4; ++i) {
#pragma unroll
    for (int r = 0; r < 4; ++r) {
      int row = m0 + i * 16 + q * 4 + r;
      if (row < M) {
        float* cp = C + (size_t)row * HID + n0 + lr;
        cp[0]  = acc[i][0][r];
        cp[16] = acc[i][1][r];
        cp[32] = acc[i][2][r];
        cp[48] = acc[i][3][r];
      }
    }
  }
}

// ---------------- aggregate: one wave per dst node -> swizzled bf16 hi/lo ----------------
__global__ __launch_bounds__(256) void k_aggregate(const float* __restrict__ T, const float* __restrict__ dinv,
                                                   const int* __restrict__ row_start, const int* __restrict__ csr_src,
                                                   const float* __restrict__ bias,
                                                   ushort* __restrict__ Ahi, ushort* __restrict__ Alo) {
  int wid = blockIdx.x * 4 + (threadIdx.x >> 6);
  int lane = threadIdx.x & 63;
  if (wid >= NN) return;
  float di = dinv[wid];
  int s = row_start[wid], e = row_start[wid + 1];
  float4 acc = make_float4(0.f, 0.f, 0.f, 0.f);
  for (int t = s; t < e; ++t) {
    int src = csr_src[t];
    float c = dinv[src] * di;
    float4 v = ((const float4*)(T + (size_t)src * HID))[lane];
    acc.x = fmaf(v.x, c, acc.x); acc.y = fmaf(v.y, c, acc.y);
    acc.z = fmaf(v.z, c, acc.z); acc.w = fmaf(v.w, c, acc.w);
  }
  float4 v = ((const float4*)(T + (size_t)wid * HID))[lane];
  float sc = di * di;
  float4 bb = ((const float4*)bias)[lane];
  acc.x = fmaf(v.x, sc, acc.x) + bb.x;
  acc.y = fmaf(v.y, sc, acc.y) + bb.y;
  acc.z = fmaf(v.z, sc, acc.z) + bb.z;
  acc.w = fmaf(v.w, sc, acc.w) + bb.w;
  ushort4 h4, l4;
  splitbf(acc.x, h4.x, l4.x); splitbf(acc.y, h4.y, l4.y);
  splitbf(acc.z, h4.z, l4.z); splitbf(acc.w, h4.w, l4.w);
  int kc = swzk(wid, lane * 4);
  *(ushort4*)(Ahi + (size_t)wid * HID + kc) = h4;
  *(ushort4*)(Alo + (size_t)wid * HID + kc) = l4;
}

// ---------------- GraphNorm (+ReLU, + pool on last layer), in-place on swizzled hi/lo ----------------
__global__ __launch_bounds__(256) void k_gnorm(ushort* __restrict__ Ahi, ushort* __restrict__ Alo,
                                               const int* __restrict__ gstart,
                                               const float* __restrict__ alpha, const float* __restrict__ gamma,
                                               const float* __restrict__ beta, float* __restrict__ pooled,
                                               int last) {
  __shared__ float4 smA[4][64];
  __shared__ float4 smB[4][64];
  int g = blockIdx.x;
  int r = threadIdx.x >> 6;        // 0..3
  int cg = threadIdx.x & 63;       // channel group
  int c0 = cg * 4;
  int s = gstart[g], e = gstart[g + 1];
  int n = e - s;
  float cnt = (float)(n > 1 ? n : 1);
  float s1[4] = {0.f, 0.f, 0.f, 0.f}, s2[4] = {0.f, 0.f, 0.f, 0.f};
  for (int i = s + r; i < e; i += 4) {
    int kc = swzk(i, c0);
    ushort4 h = *(const ushort4*)(Ahi + (size_t)i * HID + kc);
    ushort4 l = *(const ushort4*)(Alo + (size_t)i * HID + kc);
    float v0 = joinbf(h.x, l.x), v1 = joinbf(h.y, l.y), v2 = joinbf(h.z, l.z), v3 = joinbf(h.w, l.w);
    s1[0] += v0; s2[0] = fmaf(v0, v0, s2[0]);
    s1[1] += v1; s2[1] = fmaf(v1, v1, s2[1]);
    s1[2] += v2; s2[2] = fmaf(v2, v2, s2[2]);
    s1[3] += v3; s2[3] = fmaf(v3, v3, s2[3]);
  }
  smA[r][cg] = make_float4(s1[0], s1[1], s1[2], s1[3]);
  smB[r][cg] = make_float4(s2[0], s2[1], s2[2], s2[3]);
  __syncthreads();
  float4 a0 = smA[0][cg], a1 = smA[1][cg], a2 = smA[2][cg], a3 = smA[3][cg];
  float4 b0 = smB[0][cg], b1 = smB[1][cg], b2 = smB[2][cg], b3 = smB[3][cg];
  float t1[4] = {a0.x + a1.x + a2.x + a3.x, a0.y + a1.y + a2.y + a3.y,
                 a0.z + a1.z + a2.z + a3.z, a0.w + a1.w + a2.w + a3.w};
  float t2[4] = {b0.x + b1.x + b2.x + b3.x, b0.y + b1.y + b2.y + b3.y,
                 b0.z + b1.z + b2.z + b3.z, b0.w + b1.w + b2.w + b3.w};
  float4 al4 = *(const float4*)(alpha + c0);
  float4 ga4 = *(const float4*)(gamma + c0);
  float4 be4 = *(const float4*)(beta + c0);
  float am[4], rs[4], be[4];
  float alv[4] = {al4.x, al4.y, al4.z, al4.w};
  float gav[4] = {ga4.x, ga4.y, ga4.z, ga4.w};
  float bev[4] = {be4.x, be4.y, be4.z, be4.w};
#pragma unroll
  for (int j = 0; j < 4; ++j) {
    float mean = t1[j] / cnt;
    float a = alv[j] * mean;
    float var = t2[j] / cnt - 2.f * a * mean + a * a;
    am[j] = a;
    rs[j] = rsqrtf(var + EPSV) * gav[j];
    be[j] = bev[j];
  }
  if (last) {
    float p[4] = {0.f, 0.f, 0.f, 0.f};
    for (int i = s + r; i < e; i += 4) {
      int kc = swzk(i, c0);
      ushort4 h = *(const ushort4*)(Ahi + (size_t)i * HID + kc);
      ushort4 l = *(const ushort4*)(Alo + (size_t)i * HID + kc);
      float v[4] = {joinbf(h.x, l.x), joinbf(h.y, l.y), joinbf(h.z, l.z), joinbf(h.w, l.w)};
#pragma unroll
      for (int j = 0; j < 4; ++j) p[j] += fmaxf((v[j] - am[j]) * rs[j] + be[j], 0.f);
    }
    __syncthreads();   // WAR on smA
    smA[r][cg] = make_float4(p[0], p[1], p[2], p[3]);
    __syncthreads();
    if (r == 0) {
      float4 p0 = smA[0][cg], p1 = smA[1][cg], p2 = smA[2][cg], p3 = smA[3][cg];
      float4 o = make_float4(p0.x + p1.x + p2.x + p3.x, p0.y + p1.y + p2.y + p3.y,
                             p0.z + p1.z + p2.z + p3.z, p0.w + p1.w + p2.w + p3.w);
      *(float4*)(pooled + g * HID + c0) = o;
    }
  } else {
    for (int i = s + r; i < e; i += 4) {
      int kc = swzk(i, c0);
      ushort4 h = *(const ushort4*)(Ahi + (size_t)i * HID + kc);
      ushort4 l = *(const ushort4*)(Alo + (size_t)i * HID + kc);
      float v[4] = {joinbf(h.x, l.x), joinbf(h.y, l.y), joinbf(h.z, l.z), joinbf(h.w, l.w)};
      ushort4 ho, lo4;
      float o0 = fmaxf((v[0] - am[0]) * rs[0] + be[0], 0.f);
      float o1 = fmaxf((v[1] - am[1]) * rs[1] + be[1], 0.f);
      float o2 = fmaxf((v[2] - am[2]) * rs[2] + be[2], 0.f);
      float o3 = fmaxf((v[3] - am[3]) * rs[3] + be[3], 0.f);
      splitbf(o0, ho.x, lo4.x); splitbf(o1, ho.y, lo4.y);
      splitbf(o2, ho.z, lo4.z); splitbf(o3, ho.w, lo4.w);
      *(ushort4*)(Ahi + (size_t)i * HID + kc) = ho;
      *(ushort4*)(Alo + (size_t)i * HID + kc) = lo4;
    }
  }
}

// ---------------- W1 transpose ----------------
__global__ void k_transpose(const float* __restrict__ W, float* __restrict__ Wt) {
  __shared__ float tile[32][33];
  int bx = blockIdx.x, by = blockIdx.y;
  int tx = threadIdx.x, ty = threadIdx.y;   // 32 x 8
  for (int r = 0; r < 32; r += 8)
    tile[ty + r][tx] = W[(size_t)(by * 32 + ty + r) * HID + bx * 32 + tx];
  __syncthreads();
  for (int r = 0; r < 32; r += 8)
    Wt[(size_t)(bx * 32 + ty + r) * HID + by * 32 + tx] = tile[tx][ty + r];
}

// ---------------- head ----------------
__global__ __launch_bounds__(256) void k_head(const float* __restrict__ pooled, const float* __restrict__ W1t,
                                              const float* __restrict__ b1, const float* __restrict__ Wout,
                                              const float* __restrict__ bout, float* __restrict__ out) {
  int g = blockIdx.x, t = threadIdx.x;
  __shared__ float gv[HID];
  __shared__ float red[HID];
  gv[t] = pooled[g * HID + t];
  __syncthreads();
  float acc = b1[t];
  for (int k = 0; k < HID; ++k) acc = fmaf(gv[k], W1t[k * HID + t], acc);
  float h = fmaxf(acc, 0.f);
  red[t] = h * Wout[t];
  __syncthreads();
  for (int off = 128; off > 0; off >>= 1) {
    if (t < off) red[t] += red[t + off];
    __syncthreads();
  }
  if (t == 0) out[g] = 1.f / (1.f + expf(-(red[0] + bout[0])));
}

// ---------------- launch ----------------
extern "C" void kernel_launch(void* const* d_in, const int* in_sizes, int n_in,
                              void* d_out, int out_size, void* d_ws, size_t ws_size,
                              hipStream_t stream) {
  const float* x          = (const float*)d_in[0];
  const int*   edge_index = (const int*)d_in[1];
  const int*   batch      = (const int*)d_in[2];
  const float* lin0_W     = (const float*)d_in[3];
  const float* lin0_b     = (const float*)d_in[4];
  const float* conv_W     = (const float*)d_in[5];
  const float* conv_b     = (const float*)d_in[6];
  const float* n_alpha    = (const float*)d_in[7];
  const float* n_gamma    = (const float*)d_in[8];
  const float* n_beta     = (const float*)d_in[9];
  const float* lin1_W     = (const float*)d_in[10];
  const float* lin1_b     = (const float*)d_in[11];
  const float* out_W      = (const float*)d_in[12];
  const float* out_b      = (const float*)d_in[13];
  float* out = (float*)d_out;

  char* ws = (char*)d_ws;
  size_t off = 0;
  auto nxt = [&](size_t bytes) { size_t o = off; off += (bytes + 255) & ~(size_t)255; return o; };
  ushort* Ahi    = (ushort*)(ws + nxt((size_t)NN * HID * 2));   // also hosts Xhi [NN][64] until aggregate(l=0)
  ushort* Alo    = (ushort*)(ws + nxt((size_t)NN * HID * 2));   // also hosts Xlo [NN][64] until aggregate(l=0)
  float*  Tbuf   = (float*) (ws + nxt((size_t)NN * HID * 4));
  float*  dinv   = (float*) (ws + nxt((size_t)NN * 4));
  int*    deg    = (int*)   (ws + nxt((size_t)NN * 4));
  int*    rstart = (int*)   (ws + nxt((size_t)(NN + 1) * 4));
  int*    csrsrc = (int*)   (ws + nxt((size_t)NE * 4));
  int*    gstart = (int*)   (ws + nxt((size_t)(NG + 1) * 4));
  char*   poolbase = ws + nxt((size_t)NG * HID * 4);       // 2,048,000 B block, sub-carved:
  float*  pooled = (float*)poolbase;                        //   written only at layer-3 gnorm
  int*    pos    = (int*)(poolbase);                        //   [0, 400000) dead after csr_fill
  ushort* Whi    = (ushort*)(poolbase + 400384);            //   dead after last gemm
  ushort* Wlo    = (ushort*)(poolbase + 793600);            //   dead after last gemm
  float*  W1t    = (float*) (ws + nxt((size_t)HID * HID * 4));
  ushort* W0hi   = (ushort*)(ws + nxt((size_t)HID * KPAD * 2));
  ushort* W0lo   = (ushort*)(ws + nxt((size_t)HID * KPAD * 2));
  int*    part   = (int*)   (ws + nxt((size_t)NCHUNK * 4));
  ushort* Xhi    = Ahi;     // X hi/lo overlay: dead once k_l0conv completes
  ushort* Xlo    = Alo;
  (void)ws_size; (void)in_sizes; (void)n_in; (void)out_size;

  hipMemsetAsync(deg, 0, (size_t)NN * 4, stream);
  k_deg<<<(NE + 255) / 256, 256, 0, stream>>>(edge_index, deg);
  k_dinv<<<(NN + 255) / 256, 256, 0, stream>>>(deg, dinv);
  k_scanA<<<NCHUNK, 256, 0, stream>>>(deg, part);
  k_scanB<<<1, 128, 0, stream>>>(part);
  k_scanC<<<NCHUNK, 256, 0, stream>>>(deg, part, rstart, pos);
  k_csr_fill<<<(NE + 255) / 256, 256, 0, stream>>>(edge_index, pos, csrsrc);
  k_gstart<<<(NN + 255) / 256, 256, 0, stream>>>(batch, gstart);
  k_wcvt<<<(3 * HID * HID + 255) / 256, 256, 0, stream>>>(conv_W, Whi, Wlo, 3 * HID * HID);
  k_w0cvt<<<(HID * KPAD) / 256, 256, 0, stream>>>(lin0_W, W0hi, W0lo);
  k_xcvt<<<(NN + 3) / 4, 256, 0, stream>>>(x, Xhi, Xlo);
  k_transpose<<<dim3(8, 8), dim3(32, 8), 0, stream>>>(lin1_W, W1t);

  // fused lin0 + conv0 -> Tbuf  (A never hits global)
  k_l0conv<<<(NN + 63) / 64, 256, 0, stream>>>(Xhi, Xlo, W0hi, W0lo, lin0_b, Whi, Wlo, Tbuf);

  for (int l = 0; l < 3; ++l) {
    if (l > 0)
      k_gemm_mfma<<<(NN + GBM - 1) / GBM, 256, 0, stream>>>(
          Ahi, Alo, Whi + (size_t)l * HID * HID, Wlo + (size_t)l * HID * HID, Tbuf, NN);
    k_aggregate<<<(NN + 3) / 4, 256, 0, stream>>>(Tbuf, dinv, rstart, csrsrc, conv_b + l * HID, Ahi, Alo);
    k_gnorm<<<NG, 256, 0, stream>>>(Ahi, Alo, gstart, n_alpha + l * HID, n_gamma + l * HID, n_beta + l * HID,
                                    pooled, l == 2 ? 1 : 0);
  }
  k_head<<<NG, 256, 0, stream>>>(pooled, W1t, lin1_b, out_W, out_b, out);
}